// Round 8
// baseline (178.759 us; speedup 1.0000x reference)
//
#include <hip/hip_runtime.h>

#define HW 16384      // 128*128

typedef __attribute__((ext_vector_type(8))) short short8v;
typedef __attribute__((ext_vector_type(4))) float f32x4;

__device__ inline short bf16rne(float x) {
    unsigned u = __float_as_uint(x);
    unsigned r = (u + 0x7fffu + ((u >> 16) & 1u)) >> 16;
    return (short)r;
}

// ============ K1: weight prep + upsample/pack + stats-accum zero =============
// blocks 0..467: weight prep; 468..979: upsample+pack; 980: zero 256 accums.
__global__ __launch_bounds__(256) void k1_kernel(
    const float* __restrict__ W1, const float* __restrict__ W2,
    const float* __restrict__ Wk,
    short* __restrict__ Wb1, short* __restrict__ Wb2, short* __restrict__ Wbk,
    const float* __restrict__ x1, float* __restrict__ up, short* __restrict__ hcatN,
    float* __restrict__ statsAcc)
{
    int bid = blockIdx.x;
    const int t = threadIdx.x;
    if (bid == 980) {
        statsAcc[t] = 0.f;
        return;
    }
    if (bid < 468) {
        const float* W; short* Wb; int CIN, COUT, idx;
        if (bid < 288)      { W = W1; Wb = Wb1; CIN = 128; COUT = 64; idx = bid * 256 + t; }
        else if (bid < 432) { W = W2; Wb = Wb2; CIN = 64;  COUT = 64; idx = (bid - 288) * 256 + t; }
        else                { W = Wk; Wb = Wbk; CIN = 64;  COUT = 16; idx = (bid - 432) * 256 + t; }
        int NOCT = COUT >> 4, NCH = CIN >> 5;
        int total = 9 * NCH * NOCT * 512;
        if (idx >= total) return;
        int j = idx & 7, l = (idx >> 3) & 63;
        int rest = idx >> 9;
        int oct = rest % NOCT; rest /= NOCT;
        int ch = rest % NCH;
        int tap = rest / NCH;
        int o = oct * 16 + (l & 15);
        int c = ch * 32 + (l >> 4) * 8 + j;
        Wb[idx] = bf16rne(W[((size_t)o * CIN + c) * 9 + tap]);
        return;
    }
    // ---- upsample + pack ----
    __shared__ int lds[32 * 65];
    int ubid = bid - 468;
    const int xh = ubid & 1;
    const int oy = (ubid >> 1) & 127;
    const int b = ubid >> 8;
    {
        const int cw = t >> 3, pg = t & 7;
        float fy = (float)(oy * 63) / 127.f;
        int y0 = (int)fy; float wy = fy - (float)y0; int y1 = min(y0 + 1, 63);
        #pragma unroll
        for (int h = 0; h < 2; h++) {
            int c = cw * 2 + h;
            const float* sp = x1 + ((size_t)(b * 64 + c) << 12);
            float vals[8];
            #pragma unroll
            for (int i = 0; i < 8; i++) {
                int ox = xh * 64 + pg * 8 + i;
                float fx = (float)(ox * 63) / 127.f;
                int xx0 = (int)fx; float wx = fx - (float)xx0; int xx1 = min(xx0 + 1, 63);
                float v00 = sp[(y0 << 6) + xx0], v01 = sp[(y0 << 6) + xx1];
                float v10 = sp[(y1 << 6) + xx0], v11 = sp[(y1 << 6) + xx1];
                float top = v00 * (1.f - wx) + v01 * wx;
                float bot = v10 * (1.f - wx) + v11 * wx;
                vals[i] = top * (1.f - wy) + bot * wy;
            }
            float* dp = up + ((size_t)(b * 64 + c) << 14) + (oy << 7) + xh * 64 + pg * 8;
            #pragma unroll
            for (int i = 0; i < 8; i++) dp[i] = vals[i];
            #pragma unroll
            for (int i = 0; i < 8; i++) {
                unsigned wv = (unsigned)(unsigned short)bf16rne(vals[i]);
                if (h == 0) lds[cw * 65 + pg * 8 + i] = (int)wv;
                else        lds[cw * 65 + pg * 8 + i] |= (int)(wv << 16);
            }
        }
    }
    __syncthreads();
    {
        const int px = t >> 2, cq = t & 3;
        int wd[8];
        #pragma unroll
        for (int i = 0; i < 8; i++) wd[i] = lds[(cq * 8 + i) * 65 + px];
        int pixel = (oy << 7) + xh * 64 + px;
        int* dp = (int*)hcatN + (size_t)b * (HW * 64) + (size_t)pixel * 64 + 32 + cq * 8;
        *(int4*)dp = make_int4(wd[0], wd[1], wd[2], wd[3]);
        *(int4*)(dp + 4) = make_int4(wd[4], wd[5], wd[6], wd[7]);
    }
}

// ============ K2: Kf MFMA conv (blocks 0..511) + qconv (blocks 512..8703) ====
__global__ __launch_bounds__(256) void k2_kernel(
    const short* __restrict__ hcatN, const short* __restrict__ Wbk,
    const float* __restrict__ bk, float* __restrict__ Kf,
    const float* __restrict__ up, const float* __restrict__ Wq,
    const float* __restrict__ bq, float* __restrict__ Qb)
{
    const int t = threadIdx.x;
    if (blockIdx.x >= 512) {
        // ---- depthwise 3x3 + relu (streaming) ----
        int idx = (blockIdx.x - 512) * 256 + t;          // over 2*64*HW
        int hw = idx & (HW - 1);
        int bc = idx >> 14;
        int c = bc & 63;
        int y = hw >> 7, x = hw & 127;
        const float* s = up + ((size_t)bc << 14);
        const float* w = Wq + c * 9;                     // wave-uniform -> s_load
        const bool xm = (x >= 1), xp = (x <= 126);
        float acc = bq[c];
        #pragma unroll
        for (int r = 0; r < 3; r++) {
            int yy = y + r - 1;
            bool yv = ((unsigned)yy < 128u);
            const float* rp = s + (yy << 7);
            float vm = (yv && xm) ? rp[x - 1] : 0.f;
            float vc = yv         ? rp[x]     : 0.f;
            float vp = (yv && xp) ? rp[x + 1] : 0.f;
            acc = fmaf(vm, w[r * 3 + 0], acc);
            acc = fmaf(vc, w[r * 3 + 1], acc);
            acc = fmaf(vp, w[r * 3 + 2], acc);
        }
        Qb[idx] = fmaxf(acc, 0.f);
        return;
    }
    // ---- Kf = relu(conv 64->16) on NHWC ch 64..127; PSTR=128, COFF=64,
    //      CIN=64, COUT=16, NWN=1, OPW=1, MB=1, BIASRELU ----
    const int w = t >> 6, l = t & 63;
    const int wm = w;                                    // NWN=1 -> wn=0
    int bid = blockIdx.x;
    const int xseg = bid & 1; bid >>= 1;                 // SEG=2 (EXT=64)
    const int y = bid & 127;
    const int b = bid >> 7;
    const int lx = l & 15, kg = l >> 4;
    const int x = xseg * 64 + wm * 16 + lx;

    const short* abase = hcatN + (size_t)b * HW * 128 + 64 + kg * 8;
    int pxo[3]; bool pxv[3];
    #pragma unroll
    for (int d = 0; d < 3; d++) {
        int xs = x + d - 1;
        pxv[d] = ((unsigned)xs < 128u);
        int xc = xs < 0 ? 0 : (xs > 127 ? 127 : xs);
        pxo[d] = xc * 128;
    }
    const short* wbase = Wbk + (size_t)l * 8;

    f32x4 acc = (f32x4)(0.f);
    #pragma unroll
    for (int tap = 0; tap < 9; tap++) {
        const int dxi = tap % 3;
        const int ys = y + tap / 3 - 1;
        if ((unsigned)ys < 128u) {
            const short* arow = abase + (size_t)ys * 128 * 128;
            #pragma unroll
            for (int ch = 0; ch < 2; ch++) {
                short8v a = *(const short8v*)(arow + pxo[dxi] + ch * 32);
                if (!pxv[dxi]) a = (short8v)(short)0;
                short8v bf = *(const short8v*)(wbase + (size_t)(tap * 2 + ch) * 512);
                acc = __builtin_amdgcn_mfma_f32_16x16x32_bf16(a, bf, acc, 0, 0, 0);
            }
        }
    }
    const int ox = xseg * 64 + wm * 16 + kg * 4;
    const int oc = lx;
    float bb = bk[oc];
    #pragma unroll
    for (int r = 0; r < 4; r++) acc[r] = fmaxf(acc[r] + bb, 0.f);
    *(f32x4*)(Kf + (((size_t)(b * 16 + oc)) << 14) + (y << 7) + ox) = acc;
}

// ============ gate: softmax + V-gate + NHWC bf16 pack ========================
__global__ __launch_bounds__(256) void gate_kernel(
    const float* __restrict__ Qb, const float* __restrict__ Kf,
    const float* __restrict__ x2,
    const float* __restrict__ Wv, const float* __restrict__ bv,
    short* __restrict__ hcatN)
{
    __shared__ float kfs[16 * 65];
    __shared__ int tr[16 * 65];
    int bid = blockIdx.x;
    const int ch32 = bid & 1;
    const int xh = (bid >> 1) & 1;
    const int y = (bid >> 2) & 127;
    const int b = bid >> 9;
    const int t = threadIdx.x;

    {   // stage Kf tile [16 k][64 px]
        int k = t >> 4, pq = (t & 15) * 4;
        const float* sp = Kf + ((size_t)(b * 16 + k) << 14) + (y << 7) + xh * 64 + pq;
        float4 v = *(const float4*)sp;
        float* d = kfs + k * 65 + pq;
        d[0] = v.x; d[1] = v.y; d[2] = v.z; d[3] = v.w;
    }
    __syncthreads();

    const int cg = t >> 6, lane = t & 63;
    const int x = xh * 64 + lane;

    float kv[16];
    #pragma unroll
    for (int k = 0; k < 16; k++) kv[k] = kfs[k * 65 + lane];
    float kvmax = kv[0];
    #pragma unroll
    for (int k = 1; k < 16; k++) kvmax = fmaxf(kvmax, kv[k]);

    float wvv[16], bvv[16];
    #pragma unroll
    for (int k = 0; k < 16; k++) { wvv[k] = Wv[k]; bvv[k] = bv[k]; }

    float qv[4][2], xvv[4][2];
    #pragma unroll
    for (int j = 0; j < 4; j++)
        #pragma unroll
        for (int h = 0; h < 2; h++) {
            const int c = ch32 * 32 + cg * 8 + j * 2 + h;
            size_t off = ((size_t)(b * 64 + c) << 14) + (y << 7) + x;
            qv[j][h] = Qb[off];
            xvv[j][h] = x2[off];
        }

    #pragma unroll
    for (int j = 0; j < 4; j++) {
        int gpack = 0;
        #pragma unroll
        for (int h = 0; h < 2; h++) {
            float q = qv[j][h];
            float mx = q * kvmax;                         // q,kv >= 0 => exact max
            float den = 0.f, num = 0.f;
            #pragma unroll
            for (int k = 0; k < 16; k++) {
                float e = __expf(fmaf(q, kv[k], -mx));
                den += e;
                float V = fmaxf(fmaf(xvv[j][h], wvv[k], bvv[k]), 0.f);
                num = fmaf(e, V, num);
            }
            unsigned u = (unsigned)(unsigned short)bf16rne(num / den);
            gpack |= (int)(u << (h * 16));
        }
        tr[(cg * 4 + j) * 65 + lane] = gpack;
    }
    __syncthreads();
    {
        const int px = t >> 2, cq = t & 3;
        int wd[4];
        #pragma unroll
        for (int i = 0; i < 4; i++) wd[i] = tr[(cq * 4 + i) * 65 + px];
        int pixel = (y << 7) + xh * 64 + px;
        int* dp = (int*)hcatN + (size_t)b * (HW * 64) + (size_t)pixel * 64 + ch32 * 16 + cq * 4;
        *(int4*)dp = make_int4(wd[0], wd[1], wd[2], wd[3]);
    }
}

// ======== MFMA implicit-GEMM 3x3 conv + fused BN-stat atomics ================
// wave = (MB*16) px x (OPW*16) oc; block = 4 waves (NWN split oc, NWM=4/NWN x).
template<int PSTR, int COFF, int CIN, int COUT, int NWN, int OPW, int MB>
__global__ __launch_bounds__(256) void convmfma_kernel(
    const short* __restrict__ actN, const short* __restrict__ Wb,
    float* __restrict__ dst, float* __restrict__ statsAcc)
{
    constexpr int NCH = CIN / 32, NOCT = COUT / 16, NWM = 4 / NWN;
    constexpr int EXT = NWM * MB * 16;
    constexpr int SEG = 128 / EXT;
    const int t = threadIdx.x;
    const int w = t >> 6, l = t & 63;
    const int wn = w % NWN, wm = w / NWN;
    int bid = blockIdx.x;
    const int xseg = bid % SEG; bid /= SEG;
    const int y = bid & 127;
    const int b = bid >> 7;
    const int lx = l & 15, kg = l >> 4;

    const short* abase = actN + (size_t)b * HW * PSTR + COFF + kg * 8;
    int pxo[MB][3]; bool pxv[MB][3];
    #pragma unroll
    for (int m = 0; m < MB; m++) {
        int x = xseg * EXT + wm * (MB * 16) + m * 16 + lx;
        #pragma unroll
        for (int d = 0; d < 3; d++) {
            int xs = x + d - 1;
            pxv[m][d] = ((unsigned)xs < 128u);
            int xc = xs < 0 ? 0 : (xs > 127 ? 127 : xs);
            pxo[m][d] = xc * PSTR;
        }
    }
    const short* wbase = Wb + (size_t)(wn * OPW) * 512 + (size_t)l * 8;

    f32x4 acc[MB][OPW];
    #pragma unroll
    for (int m = 0; m < MB; m++)
        #pragma unroll
        for (int p = 0; p < OPW; p++) acc[m][p] = (f32x4)(0.f);

    #pragma unroll
    for (int tap = 0; tap < 9; tap++) {
        const int dxi = tap % 3;
        const int ys = y + tap / 3 - 1;
        if ((unsigned)ys < 128u) {
            const short* arow = abase + (size_t)ys * 128 * PSTR;
            #pragma unroll
            for (int ch = 0; ch < NCH; ch++) {
                short8v a[MB];
                #pragma unroll
                for (int m = 0; m < MB; m++) {
                    a[m] = *(const short8v*)(arow + pxo[m][dxi] + ch * 32);
                    if (!pxv[m][dxi]) a[m] = (short8v)(short)0;
                }
                #pragma unroll
                for (int p = 0; p < OPW; p++) {
                    short8v bf = *(const short8v*)(wbase +
                        (size_t)((tap * NCH + ch) * NOCT + p) * 512);
                    #pragma unroll
                    for (int m = 0; m < MB; m++)
                        acc[m][p] = __builtin_amdgcn_mfma_f32_16x16x32_bf16(a[m], bf, acc[m][p], 0, 0, 0);
                }
            }
        }
    }

    #pragma unroll
    for (int m = 0; m < MB; m++) {
        const int ox = xseg * EXT + wm * (MB * 16) + m * 16 + kg * 4;
        #pragma unroll
        for (int p = 0; p < OPW; p++) {
            const int oc = (wn * OPW + p) * 16 + lx;
            *(f32x4*)(dst + (((size_t)(b * COUT + oc)) << 14) + (y << 7) + ox) = acc[m][p];
        }
    }

    // fused BN partial stats: wave-local shfl reduce + one atomic per oc.
    #pragma unroll
    for (int p = 0; p < OPW; p++) {
        float s = 0.f, q2 = 0.f;
        #pragma unroll
        for (int m = 0; m < MB; m++) {
            f32x4 v = acc[m][p];
            #pragma unroll
            for (int r = 0; r < 4; r++) { s += v[r]; q2 = fmaf(v[r], v[r], q2); }
        }
        s += __shfl_xor(s, 16); q2 += __shfl_xor(q2, 16);
        s += __shfl_xor(s, 32); q2 += __shfl_xor(q2, 32);
        if (l < 16) {
            const int oc = (wn * OPW + p) * 16 + lx;
            atomicAdd(&statsAcc[oc * 2],     s);
            atomicAdd(&statsAcc[oc * 2 + 1], q2);
        }
    }
}

// ====== NCHW fp32 -> NHWC bf16 with inline-finalized BN + relu ===============
__global__ __launch_bounds__(256) void packN_kernel(
    const float* __restrict__ src, const float* __restrict__ statsAcc,
    const float* __restrict__ g, const float* __restrict__ beta,
    short* __restrict__ dstN, int PSW)
{
    __shared__ int lds[32 * 65];
    int bid = blockIdx.x;
    const int pxt = bid & 255;
    const int b = bid >> 8;
    const int t = threadIdx.x;
    {
        const int cw = t >> 3, pg = t & 7;
        #pragma unroll
        for (int h = 0; h < 2; h++) {
            int c = cw * 2 + h;
            float mean = statsAcc[c * 2] * (1.f / 32768.f);
            float var  = statsAcc[c * 2 + 1] * (1.f / 32768.f) - mean * mean;
            float sc = g[c] * rsqrtf(var + 1e-5f);
            float sh = beta[c] - mean * sc;
            const float* sp = src + ((size_t)(b * 64 + c) << 14) + pxt * 64 + pg * 8;
            float4 v0 = *(const float4*)sp;
            float4 v1 = *(const float4*)(sp + 4);
            float vals[8] = {v0.x, v0.y, v0.z, v0.w, v1.x, v1.y, v1.z, v1.w};
            #pragma unroll
            for (int i = 0; i < 8; i++) {
                float v = fmaxf(fmaf(vals[i], sc, sh), 0.f);
                unsigned wv = (unsigned)(unsigned short)bf16rne(v);
                if (h == 0) lds[cw * 65 + pg * 8 + i] = (int)wv;
                else        lds[cw * 65 + pg * 8 + i] |= (int)(wv << 16);
            }
        }
    }
    __syncthreads();
    {
        const int px = t >> 2, cq = t & 3;
        int wd[8];
        #pragma unroll
        for (int i = 0; i < 8; i++) wd[i] = lds[(cq * 8 + i) * 65 + px];
        int pixel = pxt * 64 + px;
        int* dp = (int*)dstN + (size_t)b * HW * (size_t)PSW + (size_t)pixel * PSW + cq * 8;
        *(int4*)dp = make_int4(wd[0], wd[1], wd[2], wd[3]);
        *(int4*)(dp + 4) = make_int4(wd[4], wd[5], wd[6], wd[7]);
    }
}

// ====== inline-finalized BN + relu + split o1/o2 -> d_out ====================
__global__ void norm2_kernel(const float4* __restrict__ src,
                             const float* __restrict__ statsAcc,
                             const float* __restrict__ g, const float* __restrict__ beta,
                             float4* __restrict__ out) {
    int idx4 = blockIdx.x * 256 + threadIdx.x;           // over 2*64*4096
    int q = idx4 & 4095;
    int c = (idx4 >> 12) & 63;
    int b = idx4 >> 18;
    float mean = statsAcc[c * 2] * (1.f / 32768.f);
    float var  = statsAcc[c * 2 + 1] * (1.f / 32768.f) - mean * mean;
    float sc = g[c] * rsqrtf(var + 1e-5f);
    float sh = beta[c] - mean * sc;
    float4 v = src[idx4];
    v.x = fmaxf(fmaf(v.x, sc, sh), 0.f);
    v.y = fmaxf(fmaf(v.y, sc, sh), 0.f);
    v.z = fmaxf(fmaf(v.z, sc, sh), 0.f);
    v.w = fmaxf(fmaf(v.w, sc, sh), 0.f);
    int half = c >> 5, cc = c & 31;
    out[(size_t)half * 262144 + (((size_t)(b * 32 + cc)) << 12) + q] = v;
}

extern "C" void kernel_launch(void* const* d_in, const int* in_sizes, int n_in,
                              void* d_out, int out_size, void* d_ws, size_t ws_size,
                              hipStream_t stream) {
    const float* x1 = (const float*)d_in[0];
    // d_in[1] (x1_) is unused by the reference
    const float* x2 = (const float*)d_in[2];
    const float* Wq = (const float*)d_in[3];
    const float* bq = (const float*)d_in[4];
    const float* Wk = (const float*)d_in[5];
    const float* bk = (const float*)d_in[6];
    const float* Wv = (const float*)d_in[7];
    const float* bv = (const float*)d_in[8];
    const float* W1 = (const float*)d_in[9];
    const float* g1 = (const float*)d_in[10];
    const float* b1 = (const float*)d_in[11];
    const float* W2 = (const float*)d_in[12];
    const float* g2 = (const float*)d_in[13];
    const float* b2 = (const float*)d_in[14];
    float* out = (float*)d_out;
    float* ws = (float*)d_ws;

    // workspace layout (float offsets)
    float* up     = ws;                        // [2][64][HW] fp32
    float* Qb     = ws + 2097152;              // [2][64][HW] fp32
    float* Kf     = ws + 4194304;              // [2][16][HW] fp32
    float* c1out  = ws + 4718592;              // [2][64][HW] fp32
    float* stacc  = ws + 6815744;              // 256 (acc1 @ +0, acc2 @ +128)
    short* hcatN  = (short*)(ws + 6816000);    // [2][HW][128] bf16
    short* h1N    = (short*)(ws + 8913152);    // [2][HW][64]  bf16
    short* Wb1    = (short*)(ws + 9961728);    // 9*4*4*512
    short* Wb2    = (short*)(ws + 9998592);    // 9*2*4*512
    short* Wbk    = (short*)(ws + 10017024);   // 9*2*1*512

    // K1: weight prep + upsample/pack + zero stats accumulators
    k1_kernel<<<981, 256, 0, stream>>>(W1, W2, Wk, Wb1, Wb2, Wbk, x1, up, hcatN, stacc);

    // K2: Kf conv (512 blocks) + depthwise qconv (8192 blocks)
    k2_kernel<<<8704, 256, 0, stream>>>(hcatN, Wbk, bk, Kf, up, Wq, bq, Qb);

    // K3: gate + pack (hcatN ch 0..63)
    gate_kernel<<<1024, 256, 0, stream>>>(Qb, Kf, x2, Wv, bv, hcatN);

    // K4: conv1 128->64 + BN1 stat atomics
    convmfma_kernel<128, 0, 128, 64, 2, 2, 2><<<512, 256, 0, stream>>>(
        hcatN, Wb1, c1out, stacc);

    // K5: BN1 finalize (inline) + relu + pack bf16 NHWC
    packN_kernel<<<512, 256, 0, stream>>>(c1out, stacc, g1, b1, h1N, 32);

    // K6: conv2 64->64 + BN2 stat atomics
    convmfma_kernel<64, 0, 64, 64, 2, 2, 2><<<512, 256, 0, stream>>>(
        h1N, Wb2, c1out, stacc + 128);

    // K7: BN2 finalize (inline) + relu + split -> d_out
    norm2_kernel<<<2048, 256, 0, stream>>>((const float4*)c1out, stacc + 128, g2, b2,
                                           (float4*)out);
}

// Round 10
// 108.584 us; speedup vs baseline: 1.6463x; 1.6463x over previous
//
#include <hip/hip_runtime.h>

#define HW 16384        // 128*128
#define PADPIX 16900    // 130*130 padded pixel count

typedef __attribute__((ext_vector_type(8))) short short8v;
typedef __attribute__((ext_vector_type(4))) float f32x4;

__device__ inline short bf16rne(float x) {
    unsigned u = __float_as_uint(x);
    unsigned r = (u + 0x7fffu + ((u >> 16) & 1u)) >> 16;
    return (short)r;
}

// padded-pixel index for border element j (j in 0..515)
__device__ inline int border_pp(int j) {
    if (j < 130) return j;                          // row 0
    if (j < 260) return 129 * 130 + (j - 130);      // row 129
    if (j < 388) return (j - 259) * 130;            // col 0, rows 1..128
    return (j - 387) * 130 + 129;                   // col 129, rows 1..128
}

// ===== K1: weight prep (0..467) + upsample/pack (468..979) + borders (980..1076)
__global__ __launch_bounds__(256) void k1_kernel(
    const float* __restrict__ W1, const float* __restrict__ W2,
    const float* __restrict__ Wk,
    short* __restrict__ Wb1, short* __restrict__ Wb2, short* __restrict__ Wbk,
    const float* __restrict__ x1, float* __restrict__ up,
    short* __restrict__ hcatN, short* __restrict__ h1N)
{
    int bid = blockIdx.x;
    const int t = threadIdx.x;
    if (bid < 468) {
        const float* W; short* Wb; int CIN, COUT, idx;
        if (bid < 288)      { W = W1; Wb = Wb1; CIN = 128; COUT = 64; idx = bid * 256 + t; }
        else if (bid < 432) { W = W2; Wb = Wb2; CIN = 64;  COUT = 64; idx = (bid - 288) * 256 + t; }
        else                { W = Wk; Wb = Wbk; CIN = 64;  COUT = 16; idx = (bid - 432) * 256 + t; }
        int NOCT = COUT >> 4, NCH = CIN >> 5;
        int total = 9 * NCH * NOCT * 512;
        if (idx >= total) return;
        int j = idx & 7, l = (idx >> 3) & 63;
        int rest = idx >> 9;
        int oct = rest % NOCT; rest /= NOCT;
        int ch = rest % NCH;
        int tap = rest / NCH;
        int o = oct * 16 + (l & 15);
        int c = ch * 32 + (l >> 4) * 8 + j;
        Wb[idx] = bf16rne(W[((size_t)o * CIN + c) * 9 + tap]);
        return;
    }
    if (bid < 980) {
        // ---- upsample + pack into padded hcatN ch 64..127 ----
        __shared__ int lds[32 * 65];
        int ubid = bid - 468;
        const int xh = ubid & 1;
        const int oy = (ubid >> 1) & 127;
        const int b = ubid >> 8;
        {
            const int cw = t >> 3, pg = t & 7;
            float fy = (float)(oy * 63) / 127.f;
            int y0 = (int)fy; float wy = fy - (float)y0; int y1 = min(y0 + 1, 63);
            #pragma unroll
            for (int h = 0; h < 2; h++) {
                int c = cw * 2 + h;
                const float* sp = x1 + ((size_t)(b * 64 + c) << 12);
                float vals[8];
                #pragma unroll
                for (int i = 0; i < 8; i++) {
                    int ox = xh * 64 + pg * 8 + i;
                    float fx = (float)(ox * 63) / 127.f;
                    int xx0 = (int)fx; float wx = fx - (float)xx0; int xx1 = min(xx0 + 1, 63);
                    float v00 = sp[(y0 << 6) + xx0], v01 = sp[(y0 << 6) + xx1];
                    float v10 = sp[(y1 << 6) + xx0], v11 = sp[(y1 << 6) + xx1];
                    float top = v00 * (1.f - wx) + v01 * wx;
                    float bot = v10 * (1.f - wx) + v11 * wx;
                    vals[i] = top * (1.f - wy) + bot * wy;
                }
                float* dp = up + ((size_t)(b * 64 + c) << 14) + (oy << 7) + xh * 64 + pg * 8;
                #pragma unroll
                for (int i = 0; i < 8; i++) dp[i] = vals[i];
                #pragma unroll
                for (int i = 0; i < 8; i++) {
                    unsigned wv = (unsigned)(unsigned short)bf16rne(vals[i]);
                    if (h == 0) lds[cw * 65 + pg * 8 + i] = (int)wv;
                    else        lds[cw * 65 + pg * 8 + i] |= (int)(wv << 16);
                }
            }
        }
        __syncthreads();
        {
            const int px = t >> 2, cq = t & 3;
            int wd[8];
            #pragma unroll
            for (int i = 0; i < 8; i++) wd[i] = lds[(cq * 8 + i) * 65 + px];
            int pp = (oy + 1) * 130 + xh * 64 + px + 1;
            int* dp = (int*)hcatN + ((size_t)b * PADPIX + pp) * 64 + 32 + cq * 8;
            *(int4*)dp = make_int4(wd[0], wd[1], wd[2], wd[3]);
            *(int4*)(dp + 4) = make_int4(wd[4], wd[5], wd[6], wd[7]);
        }
        return;
    }
    // ---- zero borders of hcatN (16512 int4) and h1N (8256 int4) ----
    int t2 = (bid - 980) * 256 + t;
    const int4 z = make_int4(0, 0, 0, 0);
    if (t2 < 16512) {
        int px = t2 >> 4, q = t2 & 15;
        int b = px >= 516; int j = px - b * 516;
        int pp = border_pp(j);
        ((int4*)hcatN)[((size_t)b * PADPIX + pp) * 16 + q] = z;
    } else if (t2 < 24768) {
        int idx = t2 - 16512;
        int px = idx >> 3, q = idx & 7;
        int b = px >= 516; int j = px - b * 516;
        int pp = border_pp(j);
        ((int4*)h1N)[((size_t)b * PADPIX + pp) * 8 + q] = z;
    }
}

// ===== K2: Kf MFMA conv (blocks 0..511, branchless padded) + qconv (512..8703)
__global__ __launch_bounds__(256) void k2_kernel(
    const short* __restrict__ hcatN, const short* __restrict__ Wbk,
    const float* __restrict__ bk, float* __restrict__ Kf,
    const float* __restrict__ up, const float* __restrict__ Wq,
    const float* __restrict__ bq, float* __restrict__ Qb)
{
    const int t = threadIdx.x;
    if (blockIdx.x >= 512) {
        int idx = (blockIdx.x - 512) * 256 + t;          // over 2*64*HW
        int hw = idx & (HW - 1);
        int bc = idx >> 14;
        int c = bc & 63;
        int y = hw >> 7, x = hw & 127;
        const float* s = up + ((size_t)bc << 14);
        const float* w = Wq + c * 9;                     // wave-uniform -> s_load
        const bool xm = (x >= 1), xp = (x <= 126);
        float acc = bq[c];
        #pragma unroll
        for (int r = 0; r < 3; r++) {
            int yy = y + r - 1;
            bool yv = ((unsigned)yy < 128u);
            const float* rp = s + (yy << 7);
            float vm = (yv && xm) ? rp[x - 1] : 0.f;
            float vc = yv         ? rp[x]     : 0.f;
            float vp = (yv && xp) ? rp[x + 1] : 0.f;
            acc = fmaf(vm, w[r * 3 + 0], acc);
            acc = fmaf(vc, w[r * 3 + 1], acc);
            acc = fmaf(vp, w[r * 3 + 2], acc);
        }
        Qb[idx] = fmaxf(acc, 0.f);
        return;
    }
    // ---- Kf = relu(conv 64->16), padded NHWC, branchless ----
    const int w = t >> 6, l = t & 63;
    int bid = blockIdx.x;
    const int xseg = bid & 1; bid >>= 1;
    const int y = bid & 127;
    const int b = bid >> 7;
    const int lx = l & 15, kg = l >> 4;
    const int x = xseg * 64 + w * 16 + lx;

    const short* base = hcatN + ((size_t)b * PADPIX + (size_t)y * 130 + x) * 128 + 64 + kg * 8;
    const short* wbase = Wbk + (size_t)l * 8;

    f32x4 acc = (f32x4)(0.f);
    #pragma unroll
    for (int ty = 0; ty < 3; ty++) {
        #pragma unroll
        for (int tx = 0; tx < 3; tx++) {
            const short* ab = base + (ty * 130 + tx) * 128;
            const int tap = ty * 3 + tx;
            #pragma unroll
            for (int ch = 0; ch < 2; ch++) {
                short8v a = *(const short8v*)(ab + ch * 32);
                short8v bf = *(const short8v*)(wbase + (size_t)(tap * 2 + ch) * 512);
                acc = __builtin_amdgcn_mfma_f32_16x16x32_bf16(a, bf, acc, 0, 0, 0);
            }
        }
    }
    const int ox = xseg * 64 + w * 16 + kg * 4;
    const int oc = lx;
    float bb = bk[oc];
    #pragma unroll
    for (int r = 0; r < 4; r++) acc[r] = fmaxf(acc[r] + bb, 0.f);
    *(f32x4*)(Kf + (((size_t)(b * 16 + oc)) << 14) + (y << 7) + ox) = acc;
}

// ===== gate: softmax + V-gate + padded NHWC bf16 pack ========================
__global__ __launch_bounds__(256) void gate_kernel(
    const float* __restrict__ Qb, const float* __restrict__ Kf,
    const float* __restrict__ x2,
    const float* __restrict__ Wv, const float* __restrict__ bv,
    short* __restrict__ hcatN)
{
    __shared__ float kfs[16 * 65];
    __shared__ int tr[16 * 65];
    int bid = blockIdx.x;
    const int ch32 = bid & 1;
    const int xh = (bid >> 1) & 1;
    const int y = (bid >> 2) & 127;
    const int b = bid >> 9;
    const int t = threadIdx.x;

    {   // stage Kf tile [16 k][64 px]
        int k = t >> 4, pq = (t & 15) * 4;
        const float* sp = Kf + ((size_t)(b * 16 + k) << 14) + (y << 7) + xh * 64 + pq;
        float4 v = *(const float4*)sp;
        float* d = kfs + k * 65 + pq;
        d[0] = v.x; d[1] = v.y; d[2] = v.z; d[3] = v.w;
    }
    __syncthreads();

    const int cg = t >> 6, lane = t & 63;
    const int x = xh * 64 + lane;

    float kv[16];
    #pragma unroll
    for (int k = 0; k < 16; k++) kv[k] = kfs[k * 65 + lane];
    float kvmax = kv[0];
    #pragma unroll
    for (int k = 1; k < 16; k++) kvmax = fmaxf(kvmax, kv[k]);

    float wvv[16], bvv[16];
    #pragma unroll
    for (int k = 0; k < 16; k++) { wvv[k] = Wv[k]; bvv[k] = bv[k]; }

    float qv[4][2], xvv[4][2];
    #pragma unroll
    for (int j = 0; j < 4; j++)
        #pragma unroll
        for (int h = 0; h < 2; h++) {
            const int c = ch32 * 32 + cg * 8 + j * 2 + h;
            size_t off = ((size_t)(b * 64 + c) << 14) + (y << 7) + x;
            qv[j][h] = Qb[off];
            xvv[j][h] = x2[off];
        }

    #pragma unroll
    for (int j = 0; j < 4; j++) {
        int gpack = 0;
        #pragma unroll
        for (int h = 0; h < 2; h++) {
            float q = qv[j][h];
            float mx = q * kvmax;                         // q,kv >= 0 => exact max
            float den = 0.f, num = 0.f;
            #pragma unroll
            for (int k = 0; k < 16; k++) {
                float e = __expf(fmaf(q, kv[k], -mx));
                den += e;
                float V = fmaxf(fmaf(xvv[j][h], wvv[k], bvv[k]), 0.f);
                num = fmaf(e, V, num);
            }
            unsigned u = (unsigned)(unsigned short)bf16rne(num / den);
            gpack |= (int)(u << (h * 16));
        }
        tr[(cg * 4 + j) * 65 + lane] = gpack;
    }
    __syncthreads();
    {
        const int px = t >> 2, cq = t & 3;
        int wd[4];
        #pragma unroll
        for (int i = 0; i < 4; i++) wd[i] = tr[(cq * 4 + i) * 65 + px];
        int pp = (y + 1) * 130 + xh * 64 + px + 1;
        int* dp = (int*)hcatN + ((size_t)b * PADPIX + pp) * 64 + ch32 * 16 + cq * 4;
        *(int4*)dp = make_int4(wd[0], wd[1], wd[2], wd[3]);
    }
}

// ===== MFMA implicit-GEMM 3x3 conv, padded NHWC bf16 in, NCHW fp32 out =======
// Branchless K-loop: borders are zero-filled, so no masks and no tap branches.
template<int PSTR, int CIN, int COUT, int NWN, int OPW, int MB>
__global__ __launch_bounds__(256) void convmfma_kernel(
    const short* __restrict__ actN, const short* __restrict__ Wb,
    float* __restrict__ dst)
{
    constexpr int NCH = CIN / 32, NOCT = COUT / 16, NWM = 4 / NWN;
    constexpr int EXT = NWM * MB * 16;
    constexpr int SEG = 128 / EXT;
    const int t = threadIdx.x;
    const int w = t >> 6, l = t & 63;
    const int wn = w % NWN, wm = w / NWN;
    int bid = blockIdx.x;
    const int xseg = bid % SEG; bid /= SEG;
    const int y = bid & 127;
    const int b = bid >> 7;
    const int lx = l & 15, kg = l >> 4;
    const int x = xseg * EXT + wm * (MB * 16) + lx;

    // points at padded pixel of tap (ty=0,tx=0) for this lane's first m
    const short* base = actN + ((size_t)b * PADPIX + (size_t)y * 130 + x) * PSTR + kg * 8;
    const short* wbase = Wb + (size_t)(wn * OPW) * 512 + (size_t)l * 8;

    f32x4 acc[MB][OPW];
    #pragma unroll
    for (int m = 0; m < MB; m++)
        #pragma unroll
        for (int p = 0; p < OPW; p++) acc[m][p] = (f32x4)(0.f);

    #pragma unroll
    for (int ty = 0; ty < 3; ty++) {
        #pragma unroll
        for (int tx = 0; tx < 3; tx++) {
            const short* ab = base + (ty * 130 + tx) * PSTR;
            const int tap = ty * 3 + tx;
            #pragma unroll
            for (int ch = 0; ch < NCH; ch++) {
                short8v a[MB];
                #pragma unroll
                for (int m = 0; m < MB; m++)
                    a[m] = *(const short8v*)(ab + m * 16 * PSTR + ch * 32);
                #pragma unroll
                for (int p = 0; p < OPW; p++) {
                    short8v bf = *(const short8v*)(wbase +
                        (size_t)((tap * NCH + ch) * NOCT + p) * 512);
                    #pragma unroll
                    for (int m = 0; m < MB; m++)
                        acc[m][p] = __builtin_amdgcn_mfma_f32_16x16x32_bf16(a[m], bf, acc[m][p], 0, 0, 0);
                }
            }
        }
    }

    #pragma unroll
    for (int m = 0; m < MB; m++) {
        const int ox = xseg * EXT + wm * (MB * 16) + m * 16 + kg * 4;
        #pragma unroll
        for (int p = 0; p < OPW; p++) {
            const int oc = (wn * OPW + p) * 16 + lx;
            *(f32x4*)(dst + (((size_t)(b * COUT + oc)) << 14) + (y << 7) + ox) = acc[m][p];
        }
    }
}

// ===== BN stats: one block per channel; stats = {scale[64],shift[64]} ========
__global__ void bnstats_kernel(const float* __restrict__ src, const float* __restrict__ g,
                               const float* __restrict__ beta, float* __restrict__ stats) {
    int ch = blockIdx.x;
    float s = 0.f, sq = 0.f;
    for (int b = 0; b < 2; b++) {
        const float4* p = reinterpret_cast<const float4*>(src + ((size_t)(b * 64 + ch) << 14));
        for (int i = threadIdx.x; i < 4096; i += 256) {
            float4 v = p[i];
            s += v.x + v.y + v.z + v.w;
            sq = fmaf(v.x, v.x, fmaf(v.y, v.y, fmaf(v.z, v.z, fmaf(v.w, v.w, sq))));
        }
    }
    __shared__ float sh[512];
    sh[threadIdx.x] = s;
    sh[256 + threadIdx.x] = sq;
    __syncthreads();
    for (int off = 128; off > 0; off >>= 1) {
        if ((int)threadIdx.x < off) {
            sh[threadIdx.x] += sh[threadIdx.x + off];
            sh[256 + threadIdx.x] += sh[256 + threadIdx.x + off];
        }
        __syncthreads();
    }
    if (threadIdx.x == 0) {
        float mean = sh[0] * (1.f / 32768.f);
        float var = sh[256] * (1.f / 32768.f) - mean * mean;
        float scale = g[ch] * rsqrtf(var + 1e-5f);
        stats[ch] = scale;
        stats[64 + ch] = beta[ch] - mean * scale;
    }
}

// ===== NCHW fp32 -> padded NHWC bf16 with BN+relu ============================
__global__ __launch_bounds__(256) void packN_kernel(
    const float* __restrict__ src, const float* __restrict__ stats,
    short* __restrict__ h1N)
{
    __shared__ int lds[32 * 65];
    int bid = blockIdx.x;
    const int pxt = bid & 255;
    const int b = bid >> 8;
    const int t = threadIdx.x;
    {
        const int cw = t >> 3, pg = t & 7;
        #pragma unroll
        for (int h = 0; h < 2; h++) {
            int c = cw * 2 + h;
            const float* sp = src + ((size_t)(b * 64 + c) << 14) + pxt * 64 + pg * 8;
            float sc = stats[c], sh = stats[64 + c];
            float4 v0 = *(const float4*)sp;
            float4 v1 = *(const float4*)(sp + 4);
            float vals[8] = {v0.x, v0.y, v0.z, v0.w, v1.x, v1.y, v1.z, v1.w};
            #pragma unroll
            for (int i = 0; i < 8; i++) {
                float v = fmaxf(fmaf(vals[i], sc, sh), 0.f);
                unsigned wv = (unsigned)(unsigned short)bf16rne(v);
                if (h == 0) lds[cw * 65 + pg * 8 + i] = (int)wv;
                else        lds[cw * 65 + pg * 8 + i] |= (int)(wv << 16);
            }
        }
    }
    __syncthreads();
    {
        const int px = t >> 2, cq = t & 3;
        int wd[8];
        #pragma unroll
        for (int i = 0; i < 8; i++) wd[i] = lds[(cq * 8 + i) * 65 + px];
        int pixel = pxt * 64 + px;
        int yy = pixel >> 7, xx = pixel & 127;
        int pp = (yy + 1) * 130 + xx + 1;
        int* dp = (int*)h1N + ((size_t)b * PADPIX + pp) * 32 + cq * 8;
        *(int4*)dp = make_int4(wd[0], wd[1], wd[2], wd[3]);
        *(int4*)(dp + 4) = make_int4(wd[4], wd[5], wd[6], wd[7]);
    }
}

// ===== BN + relu + split o1/o2 -> d_out ======================================
__global__ void norm2_kernel(const float4* __restrict__ src, const float* __restrict__ stats,
                             float4* __restrict__ out) {
    int idx4 = blockIdx.x * 256 + threadIdx.x;           // over 2*64*4096
    int q = idx4 & 4095;
    int c = (idx4 >> 12) & 63;
    int b = idx4 >> 18;
    float sc = stats[c], sh = stats[64 + c];
    float4 v = src[idx4];
    v.x = fmaxf(fmaf(v.x, sc, sh), 0.f);
    v.y = fmaxf(fmaf(v.y, sc, sh), 0.f);
    v.z = fmaxf(fmaf(v.z, sc, sh), 0.f);
    v.w = fmaxf(fmaf(v.w, sc, sh), 0.f);
    int half = c >> 5, cc = c & 31;
    out[(size_t)half * 262144 + (((size_t)(b * 32 + cc)) << 12) + q] = v;
}

extern "C" void kernel_launch(void* const* d_in, const int* in_sizes, int n_in,
                              void* d_out, int out_size, void* d_ws, size_t ws_size,
                              hipStream_t stream) {
    const float* x1 = (const float*)d_in[0];
    // d_in[1] (x1_) is unused by the reference
    const float* x2 = (const float*)d_in[2];
    const float* Wq = (const float*)d_in[3];
    const float* bq = (const float*)d_in[4];
    const float* Wk = (const float*)d_in[5];
    const float* bk = (const float*)d_in[6];
    const float* Wv = (const float*)d_in[7];
    const float* bv = (const float*)d_in[8];
    const float* W1 = (const float*)d_in[9];
    const float* g1 = (const float*)d_in[10];
    const float* b1 = (const float*)d_in[11];
    const float* W2 = (const float*)d_in[12];
    const float* g2 = (const float*)d_in[13];
    const float* b2 = (const float*)d_in[14];
    float* out = (float*)d_out;
    float* ws = (float*)d_ws;

    // workspace layout (float offsets) — sizes: Wb1 = 73728 shorts = 36864 f,
    // Wb2 = 36864 shorts = 18432 f, Wbk = 9216 shorts = 4608 f.
    float* up     = ws;                        // [2][64][HW] fp32
    float* Qb     = ws + 2097152;              // [2][64][HW] fp32
    float* Kf     = ws + 4194304;              // [2][16][HW] fp32
    float* c1out  = ws + 4718592;              // [2][64][HW] fp32
    float* stats  = ws + 6815744;              // 256 (stats1 @ +0, stats2 @ +128)
    short* hcatN  = (short*)(ws + 6816000);    // [2][PADPIX][128] bf16 (padded)
    short* h1N    = (short*)(ws + 8979200);    // [2][PADPIX][64]  bf16 (padded)
    short* Wb1    = (short*)(ws + 10060800);   // ends at 10097664
    short* Wb2    = (short*)(ws + 10097664);   // ends at 10116096
    short* Wbk    = (short*)(ws + 10116096);   // ends at 10120704

    // K1: weight prep + upsample/pack + border zeroing
    k1_kernel<<<1077, 256, 0, stream>>>(W1, W2, Wk, Wb1, Wb2, Wbk, x1, up, hcatN, h1N);

    // K2: Kf conv (512 blocks) + depthwise qconv (8192 blocks)
    k2_kernel<<<8704, 256, 0, stream>>>(hcatN, Wbk, bk, Kf, up, Wq, bq, Qb);

    // K3: gate + pack (hcatN ch 0..63)
    gate_kernel<<<1024, 256, 0, stream>>>(Qb, Kf, x2, Wv, bv, hcatN);

    // K4: conv1 128->64 (branchless)
    convmfma_kernel<128, 128, 64, 2, 2, 2><<<512, 256, 0, stream>>>(hcatN, Wb1, c1out);
    bnstats_kernel<<<64, 256, 0, stream>>>(c1out, g1, b1, stats);
    packN_kernel<<<512, 256, 0, stream>>>(c1out, stats, h1N);

    // K5: conv2 64->64 (branchless)
    convmfma_kernel<64, 64, 64, 2, 2, 2><<<512, 256, 0, stream>>>(h1N, Wb2, c1out);
    bnstats_kernel<<<64, 256, 0, stream>>>(c1out, g2, b2, stats + 128);
    norm2_kernel<<<2048, 256, 0, stream>>>((const float4*)c1out, stats + 128, (float4*)out);
}

// Round 11
// 104.957 us; speedup vs baseline: 1.7032x; 1.0346x over previous
//
#include <hip/hip_runtime.h>

#define HW 16384        // 128*128
#define PADPIX 16900    // 130*130 padded pixel count

typedef __attribute__((ext_vector_type(8))) short short8v;
typedef __attribute__((ext_vector_type(4))) float f32x4;

__device__ inline short bf16rne(float x) {
    unsigned u = __float_as_uint(x);
    unsigned r = (u + 0x7fffu + ((u >> 16) & 1u)) >> 16;
    return (short)r;
}

// padded-pixel index for border element j (j in 0..515)
__device__ inline int border_pp(int j) {
    if (j < 130) return j;                          // row 0
    if (j < 260) return 129 * 130 + (j - 130);      // row 129
    if (j < 388) return (j - 259) * 130;            // col 0, rows 1..128
    return (j - 387) * 130 + 129;                   // col 129, rows 1..128
}

// ===== K1: weight prep (0..467) + upsample/pack (468..979) + borders (980..1076)
//       + stats-accumulator zero (1077)
__global__ __launch_bounds__(256) void k1_kernel(
    const float* __restrict__ W1, const float* __restrict__ W2,
    const float* __restrict__ Wk,
    short* __restrict__ Wb1, short* __restrict__ Wb2, short* __restrict__ Wbk,
    const float* __restrict__ x1, float* __restrict__ up,
    short* __restrict__ hcatN, short* __restrict__ h1N,
    float* __restrict__ statsAcc)
{
    int bid = blockIdx.x;
    const int t = threadIdx.x;
    if (bid == 1077) {
        statsAcc[t] = 0.f;                           // 256 floats: acc1 + acc2
        return;
    }
    if (bid < 468) {
        const float* W; short* Wb; int CIN, COUT, idx;
        if (bid < 288)      { W = W1; Wb = Wb1; CIN = 128; COUT = 64; idx = bid * 256 + t; }
        else if (bid < 432) { W = W2; Wb = Wb2; CIN = 64;  COUT = 64; idx = (bid - 288) * 256 + t; }
        else                { W = Wk; Wb = Wbk; CIN = 64;  COUT = 16; idx = (bid - 432) * 256 + t; }
        int NOCT = COUT >> 4, NCH = CIN >> 5;
        int total = 9 * NCH * NOCT * 512;
        if (idx >= total) return;
        int j = idx & 7, l = (idx >> 3) & 63;
        int rest = idx >> 9;
        int oct = rest % NOCT; rest /= NOCT;
        int ch = rest % NCH;
        int tap = rest / NCH;
        int o = oct * 16 + (l & 15);
        int c = ch * 32 + (l >> 4) * 8 + j;
        Wb[idx] = bf16rne(W[((size_t)o * CIN + c) * 9 + tap]);
        return;
    }
    if (bid < 980) {
        // ---- upsample + pack into padded hcatN ch 64..127 ----
        __shared__ int lds[32 * 65];
        int ubid = bid - 468;
        const int xh = ubid & 1;
        const int oy = (ubid >> 1) & 127;
        const int b = ubid >> 8;
        {
            const int cw = t >> 3, pg = t & 7;
            float fy = (float)(oy * 63) / 127.f;
            int y0 = (int)fy; float wy = fy - (float)y0; int y1 = min(y0 + 1, 63);
            #pragma unroll
            for (int h = 0; h < 2; h++) {
                int c = cw * 2 + h;
                const float* sp = x1 + ((size_t)(b * 64 + c) << 12);
                float vals[8];
                #pragma unroll
                for (int i = 0; i < 8; i++) {
                    int ox = xh * 64 + pg * 8 + i;
                    float fx = (float)(ox * 63) / 127.f;
                    int xx0 = (int)fx; float wx = fx - (float)xx0; int xx1 = min(xx0 + 1, 63);
                    float v00 = sp[(y0 << 6) + xx0], v01 = sp[(y0 << 6) + xx1];
                    float v10 = sp[(y1 << 6) + xx0], v11 = sp[(y1 << 6) + xx1];
                    float top = v00 * (1.f - wx) + v01 * wx;
                    float bot = v10 * (1.f - wx) + v11 * wx;
                    vals[i] = top * (1.f - wy) + bot * wy;
                }
                float* dp = up + ((size_t)(b * 64 + c) << 14) + (oy << 7) + xh * 64 + pg * 8;
                #pragma unroll
                for (int i = 0; i < 8; i++) dp[i] = vals[i];
                #pragma unroll
                for (int i = 0; i < 8; i++) {
                    unsigned wv = (unsigned)(unsigned short)bf16rne(vals[i]);
                    if (h == 0) lds[cw * 65 + pg * 8 + i] = (int)wv;
                    else        lds[cw * 65 + pg * 8 + i] |= (int)(wv << 16);
                }
            }
        }
        __syncthreads();
        {
            const int px = t >> 2, cq = t & 3;
            int wd[8];
            #pragma unroll
            for (int i = 0; i < 8; i++) wd[i] = lds[(cq * 8 + i) * 65 + px];
            int pp = (oy + 1) * 130 + xh * 64 + px + 1;
            int* dp = (int*)hcatN + ((size_t)b * PADPIX + pp) * 64 + 32 + cq * 8;
            *(int4*)dp = make_int4(wd[0], wd[1], wd[2], wd[3]);
            *(int4*)(dp + 4) = make_int4(wd[4], wd[5], wd[6], wd[7]);
        }
        return;
    }
    // ---- zero borders of hcatN (16512 int4) and h1N (8256 int4) ----
    int t2 = (bid - 980) * 256 + t;
    const int4 z = make_int4(0, 0, 0, 0);
    if (t2 < 16512) {
        int px = t2 >> 4, q = t2 & 15;
        int b = px >= 516; int j = px - b * 516;
        int pp = border_pp(j);
        ((int4*)hcatN)[((size_t)b * PADPIX + pp) * 16 + q] = z;
    } else if (t2 < 24768) {
        int idx = t2 - 16512;
        int px = idx >> 3, q = idx & 7;
        int b = px >= 516; int j = px - b * 516;
        int pp = border_pp(j);
        ((int4*)h1N)[((size_t)b * PADPIX + pp) * 8 + q] = z;
    }
}

// ===== K2: Kf MFMA conv (blocks 0..511, branchless padded) + qconv (512..8703)
__global__ __launch_bounds__(256) void k2_kernel(
    const short* __restrict__ hcatN, const short* __restrict__ Wbk,
    const float* __restrict__ bk, float* __restrict__ Kf,
    const float* __restrict__ up, const float* __restrict__ Wq,
    const float* __restrict__ bq, float* __restrict__ Qb)
{
    const int t = threadIdx.x;
    if (blockIdx.x >= 512) {
        int idx = (blockIdx.x - 512) * 256 + t;          // over 2*64*HW
        int hw = idx & (HW - 1);
        int bc = idx >> 14;
        int c = bc & 63;
        int y = hw >> 7, x = hw & 127;
        const float* s = up + ((size_t)bc << 14);
        const float* w = Wq + c * 9;                     // wave-uniform -> s_load
        const bool xm = (x >= 1), xp = (x <= 126);
        float acc = bq[c];
        #pragma unroll
        for (int r = 0; r < 3; r++) {
            int yy = y + r - 1;
            bool yv = ((unsigned)yy < 128u);
            const float* rp = s + (yy << 7);
            float vm = (yv && xm) ? rp[x - 1] : 0.f;
            float vc = yv         ? rp[x]     : 0.f;
            float vp = (yv && xp) ? rp[x + 1] : 0.f;
            acc = fmaf(vm, w[r * 3 + 0], acc);
            acc = fmaf(vc, w[r * 3 + 1], acc);
            acc = fmaf(vp, w[r * 3 + 2], acc);
        }
        Qb[idx] = fmaxf(acc, 0.f);
        return;
    }
    // ---- Kf = relu(conv 64->16), padded NHWC, branchless ----
    const int w = t >> 6, l = t & 63;
    int bid = blockIdx.x;
    const int xseg = bid & 1; bid >>= 1;
    const int y = bid & 127;
    const int b = bid >> 7;
    const int lx = l & 15, kg = l >> 4;
    const int x = xseg * 64 + w * 16 + lx;

    const short* base = hcatN + ((size_t)b * PADPIX + (size_t)y * 130 + x) * 128 + 64 + kg * 8;
    const short* wbase = Wbk + (size_t)l * 8;

    f32x4 acc = (f32x4)(0.f);
    #pragma unroll
    for (int ty = 0; ty < 3; ty++) {
        #pragma unroll
        for (int tx = 0; tx < 3; tx++) {
            const short* ab = base + (ty * 130 + tx) * 128;
            const int tap = ty * 3 + tx;
            #pragma unroll
            for (int ch = 0; ch < 2; ch++) {
                short8v a = *(const short8v*)(ab + ch * 32);
                short8v bf = *(const short8v*)(wbase + (size_t)(tap * 2 + ch) * 512);
                acc = __builtin_amdgcn_mfma_f32_16x16x32_bf16(a, bf, acc, 0, 0, 0);
            }
        }
    }
    const int ox = xseg * 64 + w * 16 + kg * 4;
    const int oc = lx;
    float bb = bk[oc];
    #pragma unroll
    for (int r = 0; r < 4; r++) acc[r] = fmaxf(acc[r] + bb, 0.f);
    *(f32x4*)(Kf + (((size_t)(b * 16 + oc)) << 14) + (y << 7) + ox) = acc;
}

// ===== gate: softmax + V-gate + padded NHWC bf16 pack ========================
__global__ __launch_bounds__(256) void gate_kernel(
    const float* __restrict__ Qb, const float* __restrict__ Kf,
    const float* __restrict__ x2,
    const float* __restrict__ Wv, const float* __restrict__ bv,
    short* __restrict__ hcatN)
{
    __shared__ float kfs[16 * 65];
    __shared__ int tr[16 * 65];
    int bid = blockIdx.x;
    const int ch32 = bid & 1;
    const int xh = (bid >> 1) & 1;
    const int y = (bid >> 2) & 127;
    const int b = bid >> 9;
    const int t = threadIdx.x;

    {   // stage Kf tile [16 k][64 px]
        int k = t >> 4, pq = (t & 15) * 4;
        const float* sp = Kf + ((size_t)(b * 16 + k) << 14) + (y << 7) + xh * 64 + pq;
        float4 v = *(const float4*)sp;
        float* d = kfs + k * 65 + pq;
        d[0] = v.x; d[1] = v.y; d[2] = v.z; d[3] = v.w;
    }
    __syncthreads();

    const int cg = t >> 6, lane = t & 63;
    const int x = xh * 64 + lane;

    float kv[16];
    #pragma unroll
    for (int k = 0; k < 16; k++) kv[k] = kfs[k * 65 + lane];
    float kvmax = kv[0];
    #pragma unroll
    for (int k = 1; k < 16; k++) kvmax = fmaxf(kvmax, kv[k]);

    float wvv[16], bvv[16];
    #pragma unroll
    for (int k = 0; k < 16; k++) { wvv[k] = Wv[k]; bvv[k] = bv[k]; }

    float qv[4][2], xvv[4][2];
    #pragma unroll
    for (int j = 0; j < 4; j++)
        #pragma unroll
        for (int h = 0; h < 2; h++) {
            const int c = ch32 * 32 + cg * 8 + j * 2 + h;
            size_t off = ((size_t)(b * 64 + c) << 14) + (y << 7) + x;
            qv[j][h] = Qb[off];
            xvv[j][h] = x2[off];
        }

    #pragma unroll
    for (int j = 0; j < 4; j++) {
        int gpack = 0;
        #pragma unroll
        for (int h = 0; h < 2; h++) {
            float q = qv[j][h];
            float mx = q * kvmax;                         // q,kv >= 0 => exact max
            float den = 0.f, num = 0.f;
            #pragma unroll
            for (int k = 0; k < 16; k++) {
                float e = __expf(fmaf(q, kv[k], -mx));
                den += e;
                float V = fmaxf(fmaf(xvv[j][h], wvv[k], bvv[k]), 0.f);
                num = fmaf(e, V, num);
            }
            unsigned u = (unsigned)(unsigned short)bf16rne(num / den);
            gpack |= (int)(u << (h * 16));
        }
        tr[(cg * 4 + j) * 65 + lane] = gpack;
    }
    __syncthreads();
    {
        const int px = t >> 2, cq = t & 3;
        int wd[4];
        #pragma unroll
        for (int i = 0; i < 4; i++) wd[i] = tr[(cq * 4 + i) * 65 + px];
        int pp = (y + 1) * 130 + xh * 64 + px + 1;
        int* dp = (int*)hcatN + ((size_t)b * PADPIX + pp) * 64 + ch32 * 16 + cq * 4;
        *(int4*)dp = make_int4(wd[0], wd[1], wd[2], wd[3]);
    }
}

// ===== MFMA implicit-GEMM 3x3 conv, padded NHWC bf16 in, NCHW fp32 out =======
// Branchless K-loop: borders are zero-filled, so no masks and no tap branches.
template<int PSTR, int CIN, int COUT, int NWN, int OPW, int MB>
__global__ __launch_bounds__(256) void convmfma_kernel(
    const short* __restrict__ actN, const short* __restrict__ Wb,
    float* __restrict__ dst)
{
    constexpr int NCH = CIN / 32, NOCT = COUT / 16, NWM = 4 / NWN;
    constexpr int EXT = NWM * MB * 16;
    constexpr int SEG = 128 / EXT;
    const int t = threadIdx.x;
    const int w = t >> 6, l = t & 63;
    const int wn = w % NWN, wm = w / NWN;
    int bid = blockIdx.x;
    const int xseg = bid % SEG; bid /= SEG;
    const int y = bid & 127;
    const int b = bid >> 7;
    const int lx = l & 15, kg = l >> 4;
    const int x = xseg * EXT + wm * (MB * 16) + lx;

    // points at padded pixel of tap (ty=0,tx=0) for this lane's first m
    const short* base = actN + ((size_t)b * PADPIX + (size_t)y * 130 + x) * PSTR + kg * 8;
    const short* wbase = Wb + (size_t)(wn * OPW) * 512 + (size_t)l * 8;

    f32x4 acc[MB][OPW];
    #pragma unroll
    for (int m = 0; m < MB; m++)
        #pragma unroll
        for (int p = 0; p < OPW; p++) acc[m][p] = (f32x4)(0.f);

    #pragma unroll
    for (int ty = 0; ty < 3; ty++) {
        #pragma unroll
        for (int tx = 0; tx < 3; tx++) {
            const short* ab = base + (ty * 130 + tx) * PSTR;
            const int tap = ty * 3 + tx;
            #pragma unroll
            for (int ch = 0; ch < NCH; ch++) {
                short8v a[MB];
                #pragma unroll
                for (int m = 0; m < MB; m++)
                    a[m] = *(const short8v*)(ab + m * 16 * PSTR + ch * 32);
                #pragma unroll
                for (int p = 0; p < OPW; p++) {
                    short8v bf = *(const short8v*)(wbase +
                        (size_t)((tap * NCH + ch) * NOCT + p) * 512);
                    #pragma unroll
                    for (int m = 0; m < MB; m++)
                        acc[m][p] = __builtin_amdgcn_mfma_f32_16x16x32_bf16(a[m], bf, acc[m][p], 0, 0, 0);
                }
            }
        }
    }

    #pragma unroll
    for (int m = 0; m < MB; m++) {
        const int ox = xseg * EXT + wm * (MB * 16) + m * 16 + kg * 4;
        #pragma unroll
        for (int p = 0; p < OPW; p++) {
            const int oc = (wn * OPW + p) * 16 + lx;
            *(f32x4*)(dst + (((size_t)(b * COUT + oc)) << 14) + (y << 7) + ox) = acc[m][p];
        }
    }
}

// ===== BN raw-sum stats: 512 blocks = (slice 0..7) x (ch 0..63) ==============
// Each block LDS-reduces its 4096-float slice, then 2 atomicAdds of raw sums.
// (1024 atomics over 128 addresses — contention-free; accumulators zeroed in K1.)
__global__ void bnstats_kernel(const float* __restrict__ src, float* __restrict__ statsAcc) {
    int ch = blockIdx.x & 63, sl = blockIdx.x >> 6;     // sl 0..7
    int b = sl >> 2, q = sl & 3;
    const float4* p = reinterpret_cast<const float4*>(
        src + ((size_t)(b * 64 + ch) << 14) + q * 4096);
    float s = 0.f, sq = 0.f;
    for (int i = threadIdx.x; i < 1024; i += 256) {
        float4 v = p[i];
        s += v.x + v.y + v.z + v.w;
        sq = fmaf(v.x, v.x, fmaf(v.y, v.y, fmaf(v.z, v.z, fmaf(v.w, v.w, sq))));
    }
    __shared__ float sh[512];
    sh[threadIdx.x] = s;
    sh[256 + threadIdx.x] = sq;
    __syncthreads();
    for (int off = 128; off > 0; off >>= 1) {
        if ((int)threadIdx.x < off) {
            sh[threadIdx.x] += sh[threadIdx.x + off];
            sh[256 + threadIdx.x] += sh[256 + threadIdx.x + off];
        }
        __syncthreads();
    }
    if (threadIdx.x == 0) {
        atomicAdd(&statsAcc[ch * 2],     sh[0]);
        atomicAdd(&statsAcc[ch * 2 + 1], sh[256]);
    }
}

// ===== NCHW fp32 -> padded NHWC bf16 with inline-finalized BN + relu =========
__global__ __launch_bounds__(256) void packN_kernel(
    const float* __restrict__ src, const float* __restrict__ statsAcc,
    const float* __restrict__ g, const float* __restrict__ beta,
    short* __restrict__ h1N)
{
    __shared__ int lds[32 * 65];
    int bid = blockIdx.x;
    const int pxt = bid & 255;
    const int b = bid >> 8;
    const int t = threadIdx.x;
    {
        const int cw = t >> 3, pg = t & 7;
        #pragma unroll
        for (int h = 0; h < 2; h++) {
            int c = cw * 2 + h;
            float mean = statsAcc[c * 2] * (1.f / 32768.f);
            float var  = statsAcc[c * 2 + 1] * (1.f / 32768.f) - mean * mean;
            float sc = g[c] * rsqrtf(var + 1e-5f);
            float sh = beta[c] - mean * sc;
            const float* sp = src + ((size_t)(b * 64 + c) << 14) + pxt * 64 + pg * 8;
            float4 v0 = *(const float4*)sp;
            float4 v1 = *(const float4*)(sp + 4);
            float vals[8] = {v0.x, v0.y, v0.z, v0.w, v1.x, v1.y, v1.z, v1.w};
            #pragma unroll
            for (int i = 0; i < 8; i++) {
                float v = fmaxf(fmaf(vals[i], sc, sh), 0.f);
                unsigned wv = (unsigned)(unsigned short)bf16rne(v);
                if (h == 0) lds[cw * 65 + pg * 8 + i] = (int)wv;
                else        lds[cw * 65 + pg * 8 + i] |= (int)(wv << 16);
            }
        }
    }
    __syncthreads();
    {
        const int px = t >> 2, cq = t & 3;
        int wd[8];
        #pragma unroll
        for (int i = 0; i < 8; i++) wd[i] = lds[(cq * 8 + i) * 65 + px];
        int pixel = pxt * 64 + px;
        int yy = pixel >> 7, xx = pixel & 127;
        int pp = (yy + 1) * 130 + xx + 1;
        int* dp = (int*)h1N + ((size_t)b * PADPIX + pp) * 32 + cq * 8;
        *(int4*)dp = make_int4(wd[0], wd[1], wd[2], wd[3]);
        *(int4*)(dp + 4) = make_int4(wd[4], wd[5], wd[6], wd[7]);
    }
}

// ===== inline-finalized BN + relu + split o1/o2 -> d_out =====================
__global__ void norm2_kernel(const float4* __restrict__ src,
                             const float* __restrict__ statsAcc,
                             const float* __restrict__ g, const float* __restrict__ beta,
                             float4* __restrict__ out) {
    int idx4 = blockIdx.x * 256 + threadIdx.x;           // over 2*64*4096
    int q = idx4 & 4095;
    int c = (idx4 >> 12) & 63;
    int b = idx4 >> 18;
    float mean = statsAcc[c * 2] * (1.f / 32768.f);
    float var  = statsAcc[c * 2 + 1] * (1.f / 32768.f) - mean * mean;
    float sc = g[c] * rsqrtf(var + 1e-5f);
    float sh = beta[c] - mean * sc;
    float4 v = src[idx4];
    v.x = fmaxf(fmaf(v.x, sc, sh), 0.f);
    v.y = fmaxf(fmaf(v.y, sc, sh), 0.f);
    v.z = fmaxf(fmaf(v.z, sc, sh), 0.f);
    v.w = fmaxf(fmaf(v.w, sc, sh), 0.f);
    int half = c >> 5, cc = c & 31;
    out[(size_t)half * 262144 + (((size_t)(b * 32 + cc)) << 12) + q] = v;
}

extern "C" void kernel_launch(void* const* d_in, const int* in_sizes, int n_in,
                              void* d_out, int out_size, void* d_ws, size_t ws_size,
                              hipStream_t stream) {
    const float* x1 = (const float*)d_in[0];
    // d_in[1] (x1_) is unused by the reference
    const float* x2 = (const float*)d_in[2];
    const float* Wq = (const float*)d_in[3];
    const float* bq = (const float*)d_in[4];
    const float* Wk = (const float*)d_in[5];
    const float* bk = (const float*)d_in[6];
    const float* Wv = (const float*)d_in[7];
    const float* bv = (const float*)d_in[8];
    const float* W1 = (const float*)d_in[9];
    const float* g1 = (const float*)d_in[10];
    const float* b1 = (const float*)d_in[11];
    const float* W2 = (const float*)d_in[12];
    const float* g2 = (const float*)d_in[13];
    const float* b2 = (const float*)d_in[14];
    float* out = (float*)d_out;
    float* ws = (float*)d_ws;

    // workspace layout (float offsets) — sizes: Wb1 = 73728 shorts = 36864 f,
    // Wb2 = 36864 shorts = 18432 f, Wbk = 9216 shorts = 4608 f.
    float* up     = ws;                        // [2][64][HW] fp32
    float* Qb     = ws + 2097152;              // [2][64][HW] fp32
    float* Kf     = ws + 4194304;              // [2][16][HW] fp32
    float* c1out  = ws + 4718592;              // [2][64][HW] fp32
    float* stacc  = ws + 6815744;              // 256 raw sums (acc1 @ +0, acc2 @ +128)
    short* hcatN  = (short*)(ws + 6816000);    // [2][PADPIX][128] bf16 (padded)
    short* h1N    = (short*)(ws + 8979200);    // [2][PADPIX][64]  bf16 (padded)
    short* Wb1    = (short*)(ws + 10060800);   // ends at 10097664
    short* Wb2    = (short*)(ws + 10097664);   // ends at 10116096
    short* Wbk    = (short*)(ws + 10116096);   // ends at 10120704

    // K1: weight prep + upsample/pack + border zeroing + stats-acc zero
    k1_kernel<<<1078, 256, 0, stream>>>(W1, W2, Wk, Wb1, Wb2, Wbk, x1, up, hcatN, h1N,
                                        stacc);

    // K2: Kf conv (512 blocks) + depthwise qconv (8192 blocks)
    k2_kernel<<<8704, 256, 0, stream>>>(hcatN, Wbk, bk, Kf, up, Wq, bq, Qb);

    // K3: gate + pack (hcatN ch 0..63)
    gate_kernel<<<1024, 256, 0, stream>>>(Qb, Kf, x2, Wv, bv, hcatN);

    // K4: conv1 128->64 (branchless, MB=1 -> grid 1024 for occupancy)
    convmfma_kernel<128, 128, 64, 2, 2, 1><<<1024, 256, 0, stream>>>(hcatN, Wb1, c1out);
    bnstats_kernel<<<512, 256, 0, stream>>>(c1out, stacc);
    packN_kernel<<<512, 256, 0, stream>>>(c1out, stacc, g1, b1, h1N);

    // K5: conv2 64->64 (branchless, MB=1 -> grid 1024)
    convmfma_kernel<64, 64, 64, 2, 2, 1><<<1024, 256, 0, stream>>>(h1N, Wb2, c1out);
    bnstats_kernel<<<512, 256, 0, stream>>>(c1out, stacc + 128);
    norm2_kernel<<<2048, 256, 0, stream>>>((const float4*)c1out, stacc + 128, g2, b2,
                                           (float4*)out);
}

// Round 12
// 101.581 us; speedup vs baseline: 1.7598x; 1.0332x over previous
//
#include <hip/hip_runtime.h>

#define HW 16384        // 128*128
#define PADPIX 16900    // 130*130 padded pixel count

typedef __attribute__((ext_vector_type(8))) short short8v;
typedef __attribute__((ext_vector_type(4))) float f32x4;

__device__ inline short bf16rne(float x) {
    unsigned u = __float_as_uint(x);
    unsigned r = (u + 0x7fffu + ((u >> 16) & 1u)) >> 16;
    return (short)r;
}
__device__ inline float bf16tof(short s) {
    return __uint_as_float(((unsigned)(unsigned short)s) << 16);
}

// padded-pixel index for border element j (j in 0..515)
__device__ inline int border_pp(int j) {
    if (j < 130) return j;                          // row 0
    if (j < 260) return 129 * 130 + (j - 130);      // row 129
    if (j < 388) return (j - 259) * 130;            // col 0, rows 1..128
    return (j - 387) * 130 + 129;                   // col 129, rows 1..128
}

// ===== K1: weight prep (0..467) + borders (468..564) + stats-acc zero (565) ==
__global__ __launch_bounds__(256) void k1_kernel(
    const float* __restrict__ W1, const float* __restrict__ W2,
    const float* __restrict__ Wk,
    short* __restrict__ Wb1, short* __restrict__ Wb2, short* __restrict__ Wbk,
    short* __restrict__ hcatN, short* __restrict__ h1N,
    float* __restrict__ statsAcc)
{
    int bid = blockIdx.x;
    const int t = threadIdx.x;
    if (bid == 565) {
        statsAcc[t] = 0.f;                           // 256 floats: acc1 + acc2
        return;
    }
    if (bid < 468) {
        const float* W; short* Wb; int CIN, COUT, idx;
        if (bid < 288)      { W = W1; Wb = Wb1; CIN = 128; COUT = 64; idx = bid * 256 + t; }
        else if (bid < 432) { W = W2; Wb = Wb2; CIN = 64;  COUT = 64; idx = (bid - 288) * 256 + t; }
        else                { W = Wk; Wb = Wbk; CIN = 64;  COUT = 16; idx = (bid - 432) * 256 + t; }
        int NOCT = COUT >> 4, NCH = CIN >> 5;
        int total = 9 * NCH * NOCT * 512;
        if (idx >= total) return;
        int j = idx & 7, l = (idx >> 3) & 63;
        int rest = idx >> 9;
        int oct = rest % NOCT; rest /= NOCT;
        int ch = rest % NCH;
        int tap = rest / NCH;
        int o = oct * 16 + (l & 15);
        int c = ch * 32 + (l >> 4) * 8 + j;
        Wb[idx] = bf16rne(W[((size_t)o * CIN + c) * 9 + tap]);
        return;
    }
    // ---- zero borders of hcatN (16512 int4) and h1N (8256 int4) ----
    int t2 = (bid - 468) * 256 + t;
    const int4 z = make_int4(0, 0, 0, 0);
    if (t2 < 16512) {
        int px = t2 >> 4, q = t2 & 15;
        int b = px >= 516; int j = px - b * 516;
        int pp = border_pp(j);
        ((int4*)hcatN)[((size_t)b * PADPIX + pp) * 16 + q] = z;
    } else if (t2 < 24768) {
        int idx = t2 - 16512;
        int px = idx >> 3, q = idx & 7;
        int b = px >= 516; int j = px - b * 516;
        int pp = border_pp(j);
        ((int4*)h1N)[((size_t)b * PADPIX + pp) * 8 + q] = z;
    }
}

// ===== front: upsample -> (Kf MFMA | qconv | gate) -> hcatN, all in LDS ======
// block = (b, y, xh): one output row y, 64 px (x-half), all channels.
#define UPSTR 72                 // padded ch-stride of upB (16B-aligned rows)
#define UPROW (66 * UPSTR)       // shorts per upB row
__global__ __launch_bounds__(256) void front_kernel(
    const float* __restrict__ x1, const short* __restrict__ Wbk,
    const float* __restrict__ bk, const float* __restrict__ Wq,
    const float* __restrict__ bq, const float* __restrict__ x2,
    const float* __restrict__ Wv, const float* __restrict__ bv,
    short* __restrict__ hcatN)
{
    __shared__ __align__(16) short upB[3 * UPROW];   // [r][lpx 0..65][ch 0..63]
    __shared__ float kfs[16 * 68];                   // [k][lpx]
    __shared__ int tr[32 * 65];
    int bid = blockIdx.x;
    const int xh = bid & 1;
    const int y = (bid >> 1) & 127;
    const int b = bid >> 8;
    const int t = threadIdx.x;

    // ---- phase 1: upsample rows y-1..y+1 (bf16), zeros outside image ----
    #pragma unroll
    for (int r = 0; r < 3; r++) {
        int ry = y + r - 1;
        bool rv = ((unsigned)ry < 128u);
        float fy = (float)(ry * 63) / 127.f;
        int y0 = (int)fy; float wy = fy - (float)y0; int y1 = min(y0 + 1, 63);
        for (int it = 0; it < 16; it++) {            // interior: 64 px x 64 ch
            int flat = it * 256 + t;
            int px = flat & 63;
            int ch = flat >> 6;
            short outv = 0;
            if (rv) {
                int gx = xh * 64 + px;
                float fx = (float)(gx * 63) / 127.f;
                int x0 = (int)fx; float wx = fx - (float)x0; int x1i = min(x0 + 1, 63);
                const float* sp = x1 + ((size_t)(b * 64 + ch) << 12);
                float v00 = sp[(y0 << 6) + x0], v01 = sp[(y0 << 6) + x1i];
                float v10 = sp[(y1 << 6) + x0], v11 = sp[(y1 << 6) + x1i];
                float top = v00 * (1.f - wx) + v01 * wx;
                float bot = v10 * (1.f - wx) + v11 * wx;
                outv = bf16rne(top * (1.f - wy) + bot * wy);
            }
            upB[r * UPROW + (px + 1) * UPSTR + ch] = outv;
        }
        if (t < 128) {                               // halo columns lpx = 0, 65
            int ch = t & 63, side = t >> 6;
            int gx = xh * 64 + (side ? 64 : -1);
            int lpx = side ? 65 : 0;
            short outv = 0;
            if (rv && (unsigned)gx < 128u) {
                float fx = (float)(gx * 63) / 127.f;
                int x0 = (int)fx; float wx = fx - (float)x0; int x1i = min(x0 + 1, 63);
                const float* sp = x1 + ((size_t)(b * 64 + ch) << 12);
                float v00 = sp[(y0 << 6) + x0], v01 = sp[(y0 << 6) + x1i];
                float v10 = sp[(y1 << 6) + x0], v11 = sp[(y1 << 6) + x1i];
                float top = v00 * (1.f - wx) + v01 * wx;
                float bot = v10 * (1.f - wx) + v11 * wx;
                outv = bf16rne(top * (1.f - wy) + bot * wy);
            }
            upB[r * UPROW + lpx * UPSTR + ch] = outv;
        }
    }
    __syncthreads();

    // ---- phase 2: Kf = relu(conv64->16 + bk) via MFMA from upB -> kfs ----
    {
        const int w2 = t >> 6, l = t & 63;
        const int lx = l & 15, kg = l >> 4;
        const short* wbase = Wbk + (size_t)l * 8;
        f32x4 acc = (f32x4)(0.f);
        #pragma unroll
        for (int ty = 0; ty < 3; ty++) {
            #pragma unroll
            for (int tx = 0; tx < 3; tx++) {
                const short* ab = upB + ty * UPROW + (w2 * 16 + lx + tx) * UPSTR;
                #pragma unroll
                for (int ch = 0; ch < 2; ch++) {
                    short8v a = *(const short8v*)(ab + kg * 8 + ch * 32);
                    short8v bf = *(const short8v*)(wbase + (size_t)((ty * 3 + tx) * 2 + ch) * 512);
                    acc = __builtin_amdgcn_mfma_f32_16x16x32_bf16(a, bf, acc, 0, 0, 0);
                }
            }
        }
        float bb = bk[lx];
        #pragma unroll
        for (int r = 0; r < 4; r++)
            kfs[lx * 68 + (w2 * 16 + kg * 4 + r + 1)] = fmaxf(acc[r] + bb, 0.f);
    }
    __syncthreads();

    // ---- phase 3: qconv (depthwise from upB) + softmax gate -> tr ----
    {
        const int w3 = t >> 6, px = t & 63;
        const int lpx = px + 1;
        const int x = xh * 64 + px;
        float kv[16];
        #pragma unroll
        for (int k = 0; k < 16; k++) kv[k] = kfs[k * 68 + lpx];
        float kvmax = kv[0];
        #pragma unroll
        for (int k = 1; k < 16; k++) kvmax = fmaxf(kvmax, kv[k]);
        float wvv[16], bvv[16];
        #pragma unroll
        for (int k = 0; k < 16; k++) { wvv[k] = Wv[k]; bvv[k] = bv[k]; }
        float xvv[16];
        #pragma unroll
        for (int j = 0; j < 16; j++)
            xvv[j] = x2[((size_t)(b * 64 + w3 * 16 + j) << 14) + (y << 7) + x];

        #pragma unroll
        for (int jj = 0; jj < 8; jj++) {
            int gpk = 0;
            #pragma unroll
            for (int h = 0; h < 2; h++) {
                const int j = jj * 2 + h;
                const int ch = w3 * 16 + j;
                const float* wq = Wq + ch * 9;           // wave-uniform
                float q = bq[ch];
                #pragma unroll
                for (int r = 0; r < 3; r++) {
                    const short* rp = upB + r * UPROW + (lpx - 1) * UPSTR + ch;
                    q = fmaf(bf16tof(rp[0]),         wq[r * 3 + 0], q);
                    q = fmaf(bf16tof(rp[UPSTR]),     wq[r * 3 + 1], q);
                    q = fmaf(bf16tof(rp[2 * UPSTR]), wq[r * 3 + 2], q);
                }
                q = fmaxf(q, 0.f);
                float mx = q * kvmax;                    // q,kv >= 0 => exact max
                float den = 0.f, num = 0.f;
                #pragma unroll
                for (int k = 0; k < 16; k++) {
                    float e = __expf(fmaf(q, kv[k], -mx));
                    den += e;
                    float V = fmaxf(fmaf(xvv[j], wvv[k], bvv[k]), 0.f);
                    num = fmaf(e, V, num);
                }
                unsigned u = (unsigned)(unsigned short)bf16rne(num / den);
                gpk |= (int)(u << (h * 16));
            }
            tr[(w3 * 8 + jj) * 65 + px] = gpk;
        }
    }
    __syncthreads();

    // ---- phase 4: coalesced writes: gate -> ch 0..63, upB row1 -> ch 64..127
    {
        const int px = t >> 2, cq = t & 3;
        int pp = (y + 1) * 130 + xh * 64 + px + 1;
        int* dpL = (int*)hcatN + ((size_t)b * PADPIX + pp) * 64 + cq * 8;
        int wd[8];
        #pragma unroll
        for (int i = 0; i < 8; i++) wd[i] = tr[(cq * 8 + i) * 65 + px];
        *(int4*)dpL = make_int4(wd[0], wd[1], wd[2], wd[3]);
        *(int4*)(dpL + 4) = make_int4(wd[4], wd[5], wd[6], wd[7]);
        const int* us = (const int*)(upB + UPROW + (px + 1) * UPSTR) + cq * 8;
        int4 u0 = *(const int4*)us;
        int4 u1 = *(const int4*)(us + 4);
        int* dpU = (int*)hcatN + ((size_t)b * PADPIX + pp) * 64 + 32 + cq * 8;
        *(int4*)dpU = u0;
        *(int4*)(dpU + 4) = u1;
    }
}

// ===== MFMA implicit-GEMM 3x3 conv, padded NHWC bf16 in, NCHW fp32 out =======
template<int PSTR, int CIN, int COUT, int NWN, int OPW, int MB>
__global__ __launch_bounds__(256) void convmfma_kernel(
    const short* __restrict__ actN, const short* __restrict__ Wb,
    float* __restrict__ dst)
{
    constexpr int NCH = CIN / 32, NOCT = COUT / 16, NWM = 4 / NWN;
    constexpr int EXT = NWM * MB * 16;
    constexpr int SEG = 128 / EXT;
    const int t = threadIdx.x;
    const int w = t >> 6, l = t & 63;
    const int wn = w % NWN, wm = w / NWN;
    int bid = blockIdx.x;
    const int xseg = bid % SEG; bid /= SEG;
    const int y = bid & 127;
    const int b = bid >> 7;
    const int lx = l & 15, kg = l >> 4;
    const int x = xseg * EXT + wm * (MB * 16) + lx;

    const short* base = actN + ((size_t)b * PADPIX + (size_t)y * 130 + x) * PSTR + kg * 8;
    const short* wbase = Wb + (size_t)(wn * OPW) * 512 + (size_t)l * 8;

    f32x4 acc[MB][OPW];
    #pragma unroll
    for (int m = 0; m < MB; m++)
        #pragma unroll
        for (int p = 0; p < OPW; p++) acc[m][p] = (f32x4)(0.f);

    #pragma unroll
    for (int ty = 0; ty < 3; ty++) {
        #pragma unroll
        for (int tx = 0; tx < 3; tx++) {
            const short* ab = base + (ty * 130 + tx) * PSTR;
            const int tap = ty * 3 + tx;
            #pragma unroll
            for (int ch = 0; ch < NCH; ch++) {
                short8v a[MB];
                #pragma unroll
                for (int m = 0; m < MB; m++)
                    a[m] = *(const short8v*)(ab + m * 16 * PSTR + ch * 32);
                #pragma unroll
                for (int p = 0; p < OPW; p++) {
                    short8v bf = *(const short8v*)(wbase +
                        (size_t)((tap * NCH + ch) * NOCT + p) * 512);
                    #pragma unroll
                    for (int m = 0; m < MB; m++)
                        acc[m][p] = __builtin_amdgcn_mfma_f32_16x16x32_bf16(a[m], bf, acc[m][p], 0, 0, 0);
                }
            }
        }
    }

    #pragma unroll
    for (int m = 0; m < MB; m++) {
        const int ox = xseg * EXT + wm * (MB * 16) + m * 16 + kg * 4;
        #pragma unroll
        for (int p = 0; p < OPW; p++) {
            const int oc = (wn * OPW + p) * 16 + lx;
            *(f32x4*)(dst + (((size_t)(b * COUT + oc)) << 14) + (y << 7) + ox) = acc[m][p];
        }
    }
}

// ===== BN raw-sum stats: 512 blocks = (slice 0..7) x (ch 0..63) ==============
__global__ void bnstats_kernel(const float* __restrict__ src, float* __restrict__ statsAcc) {
    int ch = blockIdx.x & 63, sl = blockIdx.x >> 6;     // sl 0..7
    int b = sl >> 2, q = sl & 3;
    const float4* p = reinterpret_cast<const float4*>(
        src + ((size_t)(b * 64 + ch) << 14) + q * 4096);
    float s = 0.f, sq = 0.f;
    for (int i = threadIdx.x; i < 1024; i += 256) {
        float4 v = p[i];
        s += v.x + v.y + v.z + v.w;
        sq = fmaf(v.x, v.x, fmaf(v.y, v.y, fmaf(v.z, v.z, fmaf(v.w, v.w, sq))));
    }
    __shared__ float sh[512];
    sh[threadIdx.x] = s;
    sh[256 + threadIdx.x] = sq;
    __syncthreads();
    for (int off = 128; off > 0; off >>= 1) {
        if ((int)threadIdx.x < off) {
            sh[threadIdx.x] += sh[threadIdx.x + off];
            sh[256 + threadIdx.x] += sh[256 + threadIdx.x + off];
        }
        __syncthreads();
    }
    if (threadIdx.x == 0) {
        atomicAdd(&statsAcc[ch * 2],     sh[0]);
        atomicAdd(&statsAcc[ch * 2 + 1], sh[256]);
    }
}

// ===== NCHW fp32 -> padded NHWC bf16 with inline-finalized BN + relu =========
__global__ __launch_bounds__(256) void packN_kernel(
    const float* __restrict__ src, const float* __restrict__ statsAcc,
    const float* __restrict__ g, const float* __restrict__ beta,
    short* __restrict__ h1N)
{
    __shared__ int lds[32 * 65];
    int bid = blockIdx.x;
    const int pxt = bid & 255;
    const int b = bid >> 8;
    const int t = threadIdx.x;
    {
        const int cw = t >> 3, pg = t & 7;
        #pragma unroll
        for (int h = 0; h < 2; h++) {
            int c = cw * 2 + h;
            float mean = statsAcc[c * 2] * (1.f / 32768.f);
            float var  = statsAcc[c * 2 + 1] * (1.f / 32768.f) - mean * mean;
            float sc = g[c] * rsqrtf(var + 1e-5f);
            float sh = beta[c] - mean * sc;
            const float* sp = src + ((size_t)(b * 64 + c) << 14) + pxt * 64 + pg * 8;
            float4 v0 = *(const float4*)sp;
            float4 v1 = *(const float4*)(sp + 4);
            float vals[8] = {v0.x, v0.y, v0.z, v0.w, v1.x, v1.y, v1.z, v1.w};
            #pragma unroll
            for (int i = 0; i < 8; i++) {
                float v = fmaxf(fmaf(vals[i], sc, sh), 0.f);
                unsigned wv = (unsigned)(unsigned short)bf16rne(v);
                if (h == 0) lds[cw * 65 + pg * 8 + i] = (int)wv;
                else        lds[cw * 65 + pg * 8 + i] |= (int)(wv << 16);
            }
        }
    }
    __syncthreads();
    {
        const int px = t >> 2, cq = t & 3;
        int wd[8];
        #pragma unroll
        for (int i = 0; i < 8; i++) wd[i] = lds[(cq * 8 + i) * 65 + px];
        int pixel = pxt * 64 + px;
        int yy = pixel >> 7, xx = pixel & 127;
        int pp = (yy + 1) * 130 + xx + 1;
        int* dp = (int*)h1N + ((size_t)b * PADPIX + pp) * 32 + cq * 8;
        *(int4*)dp = make_int4(wd[0], wd[1], wd[2], wd[3]);
        *(int4*)(dp + 4) = make_int4(wd[4], wd[5], wd[6], wd[7]);
    }
}

// ===== inline-finalized BN + relu + split o1/o2 -> d_out =====================
__global__ void norm2_kernel(const float4* __restrict__ src,
                             const float* __restrict__ statsAcc,
                             const float* __restrict__ g, const float* __restrict__ beta,
                             float4* __restrict__ out) {
    int idx4 = blockIdx.x * 256 + threadIdx.x;           // over 2*64*4096
    int q = idx4 & 4095;
    int c = (idx4 >> 12) & 63;
    int b = idx4 >> 18;
    float mean = statsAcc[c * 2] * (1.f / 32768.f);
    float var  = statsAcc[c * 2 + 1] * (1.f / 32768.f) - mean * mean;
    float sc = g[c] * rsqrtf(var + 1e-5f);
    float sh = beta[c] - mean * sc;
    float4 v = src[idx4];
    v.x = fmaxf(fmaf(v.x, sc, sh), 0.f);
    v.y = fmaxf(fmaf(v.y, sc, sh), 0.f);
    v.z = fmaxf(fmaf(v.z, sc, sh), 0.f);
    v.w = fmaxf(fmaf(v.w, sc, sh), 0.f);
    int half = c >> 5, cc = c & 31;
    out[(size_t)half * 262144 + (((size_t)(b * 32 + cc)) << 12) + q] = v;
}

extern "C" void kernel_launch(void* const* d_in, const int* in_sizes, int n_in,
                              void* d_out, int out_size, void* d_ws, size_t ws_size,
                              hipStream_t stream) {
    const float* x1 = (const float*)d_in[0];
    // d_in[1] (x1_) is unused by the reference
    const float* x2 = (const float*)d_in[2];
    const float* Wq = (const float*)d_in[3];
    const float* bq = (const float*)d_in[4];
    const float* Wk = (const float*)d_in[5];
    const float* bk = (const float*)d_in[6];
    const float* Wv = (const float*)d_in[7];
    const float* bv = (const float*)d_in[8];
    const float* W1 = (const float*)d_in[9];
    const float* g1 = (const float*)d_in[10];
    const float* b1 = (const float*)d_in[11];
    const float* W2 = (const float*)d_in[12];
    const float* g2 = (const float*)d_in[13];
    const float* b2 = (const float*)d_in[14];
    float* out = (float*)d_out;
    float* ws = (float*)d_ws;

    // workspace layout (float offsets)
    float* c1out  = ws;                        // [2][64][HW] fp32      (2,097,152)
    float* stacc  = ws + 2097152;              // 256 raw sums
    short* hcatN  = (short*)(ws + 2097408);    // [2][PADPIX][128] bf16 (2,163,200 f)
    short* h1N    = (short*)(ws + 4260608);    // [2][PADPIX][64]  bf16 (1,081,600 f)
    short* Wb1    = (short*)(ws + 5342208);    // 73728 shorts = 36864 f
    short* Wb2    = (short*)(ws + 5379072);    // 36864 shorts = 18432 f
    short* Wbk    = (short*)(ws + 5397504);    // 9216 shorts  =  4608 f

    // K1: weight prep + border zeroing + stats-acc zero
    k1_kernel<<<566, 256, 0, stream>>>(W1, W2, Wk, Wb1, Wb2, Wbk, hcatN, h1N, stacc);

    // front: upsample + Kf conv + qconv + gate, fused -> hcatN (both halves)
    front_kernel<<<512, 256, 0, stream>>>(x1, Wbk, bk, Wq, bq, x2, Wv, bv, hcatN);

    // conv1 128->64 (branchless, MB=1 -> grid 1024)
    convmfma_kernel<128, 128, 64, 2, 2, 1><<<1024, 256, 0, stream>>>(hcatN, Wb1, c1out);
    bnstats_kernel<<<512, 256, 0, stream>>>(c1out, stacc);
    packN_kernel<<<512, 256, 0, stream>>>(c1out, stacc, g1, b1, h1N);

    // conv2 64->64 (branchless, MB=1 -> grid 1024)
    convmfma_kernel<64, 64, 64, 2, 2, 1><<<1024, 256, 0, stream>>>(h1N, Wb2, c1out);
    bnstats_kernel<<<512, 256, 0, stream>>>(c1out, stacc + 128);
    norm2_kernel<<<2048, 256, 0, stream>>>((const float4*)c1out, stacc + 128, g2, b2,
                                           (float4*)out);
}

// Round 13
// 94.239 us; speedup vs baseline: 1.8969x; 1.0779x over previous
//
#include <hip/hip_runtime.h>

#define HW 16384        // 128*128
#define PADPIX 16900    // 130*130 padded pixel count

typedef __attribute__((ext_vector_type(8))) short short8v;
typedef __attribute__((ext_vector_type(4))) float f32x4;

__device__ inline short bf16rne(float x) {
    unsigned u = __float_as_uint(x);
    unsigned r = (u + 0x7fffu + ((u >> 16) & 1u)) >> 16;
    return (short)r;
}
__device__ inline float bf16tof(short s) {
    return __uint_as_float(((unsigned)(unsigned short)s) << 16);
}

// padded-pixel index for border element j (j in 0..515)
__device__ inline int border_pp(int j) {
    if (j < 130) return j;                          // row 0
    if (j < 260) return 129 * 130 + (j - 130);      // row 129
    if (j < 388) return (j - 259) * 130;            // col 0, rows 1..128
    return (j - 387) * 130 + 129;                   // col 129, rows 1..128
}

// ===== K1: weight prep (0..467) + borders (468..564) + stats-acc zero (565) ==
__global__ __launch_bounds__(256) void k1_kernel(
    const float* __restrict__ W1, const float* __restrict__ W2,
    const float* __restrict__ Wk,
    short* __restrict__ Wb1, short* __restrict__ Wb2, short* __restrict__ Wbk,
    short* __restrict__ hcatN, short* __restrict__ h1N,
    float* __restrict__ statsAcc)
{
    int bid = blockIdx.x;
    const int t = threadIdx.x;
    if (bid == 565) {
        statsAcc[t] = 0.f;                           // 256 floats: acc1 + acc2
        return;
    }
    if (bid < 468) {
        const float* W; short* Wb; int CIN, COUT, idx;
        if (bid < 288)      { W = W1; Wb = Wb1; CIN = 128; COUT = 64; idx = bid * 256 + t; }
        else if (bid < 432) { W = W2; Wb = Wb2; CIN = 64;  COUT = 64; idx = (bid - 288) * 256 + t; }
        else                { W = Wk; Wb = Wbk; CIN = 64;  COUT = 16; idx = (bid - 432) * 256 + t; }
        int NOCT = COUT >> 4, NCH = CIN >> 5;
        int total = 9 * NCH * NOCT * 512;
        if (idx >= total) return;
        int j = idx & 7, l = (idx >> 3) & 63;
        int rest = idx >> 9;
        int oct = rest % NOCT; rest /= NOCT;
        int ch = rest % NCH;
        int tap = rest / NCH;
        int o = oct * 16 + (l & 15);
        int c = ch * 32 + (l >> 4) * 8 + j;
        Wb[idx] = bf16rne(W[((size_t)o * CIN + c) * 9 + tap]);
        return;
    }
    // ---- zero borders of hcatN (16512 int4) and h1N (8256 int4) ----
    int t2 = (bid - 468) * 256 + t;
    const int4 z = make_int4(0, 0, 0, 0);
    if (t2 < 16512) {
        int px = t2 >> 4, q = t2 & 15;
        int b = px >= 516; int j = px - b * 516;
        int pp = border_pp(j);
        ((int4*)hcatN)[((size_t)b * PADPIX + pp) * 16 + q] = z;
    } else if (t2 < 24768) {
        int idx = t2 - 16512;
        int px = idx >> 3, q = idx & 7;
        int b = px >= 516; int j = px - b * 516;
        int pp = border_pp(j);
        ((int4*)h1N)[((size_t)b * PADPIX + pp) * 8 + q] = z;
    }
}

// ===== front: upsample -> (Kf MFMA || qconv) -> gate -> hcatN, all in LDS ====
// block = (b, y, xq): one output row y, 32 px (x-quarter), all channels.
#define UPSTR 72                 // ch-stride of upB in shorts (16B-aligned)
#define UPROW (34 * UPSTR)       // shorts per upB row (34 lpx)
__global__ __launch_bounds__(256) void front_kernel(
    const float* __restrict__ x1, const short* __restrict__ Wbk,
    const float* __restrict__ bk, const float* __restrict__ Wq,
    const float* __restrict__ bq, const float* __restrict__ x2,
    const float* __restrict__ Wv, const float* __restrict__ bv,
    short* __restrict__ hcatN)
{
    __shared__ __align__(16) short upB[3 * UPROW];   // [r][lpx 0..33][ch 0..63]
    __shared__ float kfs[16 * 33];                   // [k][px 0..31], stride 33
    __shared__ float qbuf[32 * 65];                  // [px][ch], stride 65
    __shared__ int tr[32 * 33];                      // [chpair][px], stride 33
    int bid = blockIdx.x;
    const int xq = bid & 3;
    const int y = (bid >> 2) & 127;
    const int b = bid >> 9;
    const int t = threadIdx.x;
    const int X0 = xq * 32;

    // ---- phase 1: upsample rows y-1..y+1 (bf16) into upB, zeros outside ----
    {
        const int px1 = t & 31, cg1 = t >> 5;        // 32 px x 8 ch-groups
        const int gx = X0 + px1;
        float fx = (float)(gx * 63) / 127.f;
        int x0 = (int)fx; float wx = fx - (float)x0; int x1i = min(x0 + 1, 63);
        #pragma unroll
        for (int r = 0; r < 3; r++) {
            int ry = y + r - 1;
            bool rv = ((unsigned)ry < 128u);
            int ryc = rv ? ry : 0;
            float fy = (float)(ryc * 63) / 127.f;
            int y0 = (int)fy; float wy = fy - (float)y0; int y1 = min(y0 + 1, 63);
            int pk[4];
            #pragma unroll
            for (int jj = 0; jj < 4; jj++) {
                unsigned lohi[2];
                #pragma unroll
                for (int h = 0; h < 2; h++) {
                    int ch = cg1 * 8 + jj * 2 + h;
                    float v = 0.f;
                    if (rv) {
                        const float* sp = x1 + ((size_t)(b * 64 + ch) << 12);
                        float v00 = sp[(y0 << 6) + x0], v01 = sp[(y0 << 6) + x1i];
                        float v10 = sp[(y1 << 6) + x0], v11 = sp[(y1 << 6) + x1i];
                        float top = v00 * (1.f - wx) + v01 * wx;
                        float bot = v10 * (1.f - wx) + v11 * wx;
                        v = top * (1.f - wy) + bot * wy;
                    }
                    lohi[h] = (unsigned)(unsigned short)bf16rne(v);
                }
                pk[jj] = (int)(lohi[0] | (lohi[1] << 16));
            }
            *(int4*)(upB + r * UPROW + (px1 + 1) * UPSTR + cg1 * 8) =
                make_int4(pk[0], pk[1], pk[2], pk[3]);
        }
        if (t < 48) {                                // halo: r x side x cg
            int r = t >> 4, side = (t >> 3) & 1, cg = t & 7;
            int gxh = X0 + (side ? 32 : -1);
            int lpx = side ? 33 : 0;
            int ry = y + r - 1;
            bool v_ok = ((unsigned)ry < 128u) && ((unsigned)gxh < 128u);
            int ryc = ((unsigned)ry < 128u) ? ry : 0;
            float fy = (float)(ryc * 63) / 127.f;
            int y0 = (int)fy; float wy = fy - (float)y0; int y1 = min(y0 + 1, 63);
            int gxc = min(max(gxh, 0), 127);
            float fxh = (float)(gxc * 63) / 127.f;
            int hx0 = (int)fxh; float hwx = fxh - (float)hx0; int hx1 = min(hx0 + 1, 63);
            int pk[4];
            #pragma unroll
            for (int jj = 0; jj < 4; jj++) {
                unsigned lohi[2];
                #pragma unroll
                for (int h = 0; h < 2; h++) {
                    int ch = cg * 8 + jj * 2 + h;
                    float v = 0.f;
                    if (v_ok) {
                        const float* sp = x1 + ((size_t)(b * 64 + ch) << 12);
                        float v00 = sp[(y0 << 6) + hx0], v01 = sp[(y0 << 6) + hx1];
                        float v10 = sp[(y1 << 6) + hx0], v11 = sp[(y1 << 6) + hx1];
                        float top = v00 * (1.f - hwx) + v01 * hwx;
                        float bot = v10 * (1.f - hwx) + v11 * hwx;
                        v = top * (1.f - wy) + bot * wy;
                    }
                    lohi[h] = (unsigned)(unsigned short)bf16rne(v);
                }
                pk[jj] = (int)(lohi[0] | (lohi[1] << 16));
            }
            *(int4*)(upB + r * UPROW + lpx * UPSTR + cg * 8) =
                make_int4(pk[0], pk[1], pk[2], pk[3]);
        }
    }
    __syncthreads();

    // ---- phase 2: waves 0-1: Kf MFMA (16 px each); waves 2-3: qconv --------
    {
        const int w = t >> 6, l = t & 63;
        if (w < 2) {
            const int lx = l & 15, kg = l >> 4;
            const short* wbase = Wbk + (size_t)l * 8;
            f32x4 acc = (f32x4)(0.f);
            #pragma unroll
            for (int ty = 0; ty < 3; ty++) {
                #pragma unroll
                for (int tx = 0; tx < 3; tx++) {
                    const short* ab = upB + ty * UPROW + (size_t)(w * 16 + lx + tx) * UPSTR;
                    #pragma unroll
                    for (int ch = 0; ch < 2; ch++) {
                        short8v a = *(const short8v*)(ab + kg * 8 + ch * 32);
                        short8v bf = *(const short8v*)(wbase +
                            (size_t)((ty * 3 + tx) * 2 + ch) * 512);
                        acc = __builtin_amdgcn_mfma_f32_16x16x32_bf16(a, bf, acc, 0, 0, 0);
                    }
                }
            }
            float bb = bk[lx];
            #pragma unroll
            for (int r = 0; r < 4; r++)
                kfs[lx * 33 + (w * 16 + kg * 4 + r)] = fmaxf(acc[r] + bb, 0.f);
        } else {
            // depthwise qconv, ch-major sliding window (conflict-free LDS reads)
            const int ch = l;
            const int px0 = (w - 2) * 16;
            const float* wqp = Wq + ch * 9;
            float wq[9];
            #pragma unroll
            for (int i = 0; i < 9; i++) wq[i] = wqp[i];
            float bqc = bq[ch];
            float a0[3], a1[3];
            #pragma unroll
            for (int r = 0; r < 3; r++) {
                a0[r] = bf16tof(upB[r * UPROW + px0 * UPSTR + ch]);
                a1[r] = bf16tof(upB[r * UPROW + (px0 + 1) * UPSTR + ch]);
            }
            for (int p = 0; p < 16; p++) {
                float a2[3];
                #pragma unroll
                for (int r = 0; r < 3; r++)
                    a2[r] = bf16tof(upB[r * UPROW + (px0 + p + 2) * UPSTR + ch]);
                float q = bqc;
                #pragma unroll
                for (int r = 0; r < 3; r++)
                    q = fmaf(a0[r], wq[r * 3 + 0],
                        fmaf(a1[r], wq[r * 3 + 1], fmaf(a2[r], wq[r * 3 + 2], q)));
                qbuf[(px0 + p) * 65 + ch] = fmaxf(q, 0.f);
                #pragma unroll
                for (int r = 0; r < 3; r++) { a0[r] = a1[r]; a1[r] = a2[r]; }
            }
        }
    }
    __syncthreads();

    // ---- phase 3: softmax gate, 32 px x 64 ch -------------------------------
    {
        const int px = t & 31, cg = t >> 5;
        const int x = X0 + px;
        float kv[16];
        #pragma unroll
        for (int k = 0; k < 16; k++) kv[k] = kfs[k * 33 + px];
        float kvmax = kv[0];
        #pragma unroll
        for (int k = 1; k < 16; k++) kvmax = fmaxf(kvmax, kv[k]);
        float wvv[16], bvv[16];
        #pragma unroll
        for (int k = 0; k < 16; k++) { wvv[k] = Wv[k]; bvv[k] = bv[k]; }
        float xvv[8], qv[8];
        #pragma unroll
        for (int j = 0; j < 8; j++) {
            xvv[j] = x2[((size_t)(b * 64 + cg * 8 + j) << 14) + (y << 7) + x];
            qv[j] = qbuf[px * 65 + cg * 8 + j];
        }
        #pragma unroll
        for (int jj = 0; jj < 4; jj++) {
            int gpk = 0;
            #pragma unroll
            for (int h = 0; h < 2; h++) {
                const int j = jj * 2 + h;
                float q = qv[j];
                float mx = q * kvmax;                // q,kv >= 0 => exact max
                float den = 0.f, num = 0.f;
                #pragma unroll
                for (int k = 0; k < 16; k++) {
                    float e = __expf(fmaf(q, kv[k], -mx));
                    den += e;
                    float V = fmaxf(fmaf(xvv[j], wvv[k], bvv[k]), 0.f);
                    num = fmaf(e, V, num);
                }
                unsigned u = (unsigned)(unsigned short)bf16rne(num / den);
                gpk |= (int)(u << (h * 16));
            }
            tr[(cg * 4 + jj) * 33 + px] = gpk;
        }
    }
    __syncthreads();

    // ---- phase 4: coalesced writes: gate -> ch 0..63, upB row1 -> ch 64..127
    {
        const int px4 = t >> 3, cq = t & 7;
        int pp = (y + 1) * 130 + X0 + px4 + 1;
        int wd[4];
        #pragma unroll
        for (int i = 0; i < 4; i++) wd[i] = tr[(cq * 4 + i) * 33 + px4];
        int* dpL = (int*)hcatN + ((size_t)b * PADPIX + pp) * 64 + cq * 4;
        *(int4*)dpL = make_int4(wd[0], wd[1], wd[2], wd[3]);
        const short* us = upB + UPROW + (size_t)(px4 + 1) * UPSTR + cq * 8;
        int4 u = *(const int4*)us;
        int* dpU = (int*)hcatN + ((size_t)b * PADPIX + pp) * 64 + 32 + cq * 4;
        *(int4*)dpU = u;
    }
}

// ===== MFMA implicit-GEMM 3x3 conv, padded NHWC bf16 in, NCHW fp32 out =======
template<int PSTR, int CIN, int COUT, int NWN, int OPW, int MB>
__global__ __launch_bounds__(256) void convmfma_kernel(
    const short* __restrict__ actN, const short* __restrict__ Wb,
    float* __restrict__ dst)
{
    constexpr int NCH = CIN / 32, NOCT = COUT / 16, NWM = 4 / NWN;
    constexpr int EXT = NWM * MB * 16;
    constexpr int SEG = 128 / EXT;
    const int t = threadIdx.x;
    const int w = t >> 6, l = t & 63;
    const int wn = w % NWN, wm = w / NWN;
    int bid = blockIdx.x;
    const int xseg = bid % SEG; bid /= SEG;
    const int y = bid & 127;
    const int b = bid >> 7;
    const int lx = l & 15, kg = l >> 4;
    const int x = xseg * EXT + wm * (MB * 16) + lx;

    const short* base = actN + ((size_t)b * PADPIX + (size_t)y * 130 + x) * PSTR + kg * 8;
    const short* wbase = Wb + (size_t)(wn * OPW) * 512 + (size_t)l * 8;

    f32x4 acc[MB][OPW];
    #pragma unroll
    for (int m = 0; m < MB; m++)
        #pragma unroll
        for (int p = 0; p < OPW; p++) acc[m][p] = (f32x4)(0.f);

    #pragma unroll
    for (int ty = 0; ty < 3; ty++) {
        #pragma unroll
        for (int tx = 0; tx < 3; tx++) {
            const short* ab = base + (ty * 130 + tx) * PSTR;
            const int tap = ty * 3 + tx;
            #pragma unroll
            for (int ch = 0; ch < NCH; ch++) {
                short8v a[MB];
                #pragma unroll
                for (int m = 0; m < MB; m++)
                    a[m] = *(const short8v*)(ab + m * 16 * PSTR + ch * 32);
                #pragma unroll
                for (int p = 0; p < OPW; p++) {
                    short8v bf = *(const short8v*)(wbase +
                        (size_t)((tap * NCH + ch) * NOCT + p) * 512);
                    #pragma unroll
                    for (int m = 0; m < MB; m++)
                        acc[m][p] = __builtin_amdgcn_mfma_f32_16x16x32_bf16(a[m], bf, acc[m][p], 0, 0, 0);
                }
            }
        }
    }

    #pragma unroll
    for (int m = 0; m < MB; m++) {
        const int ox = xseg * EXT + wm * (MB * 16) + m * 16 + kg * 4;
        #pragma unroll
        for (int p = 0; p < OPW; p++) {
            const int oc = (wn * OPW + p) * 16 + lx;
            *(f32x4*)(dst + (((size_t)(b * COUT + oc)) << 14) + (y << 7) + ox) = acc[m][p];
        }
    }
}

// ===== BN raw-sum stats: 512 blocks = (slice 0..7) x (ch 0..63) ==============
__global__ void bnstats_kernel(const float* __restrict__ src, float* __restrict__ statsAcc) {
    int ch = blockIdx.x & 63, sl = blockIdx.x >> 6;     // sl 0..7
    int b = sl >> 2, q = sl & 3;
    const float4* p = reinterpret_cast<const float4*>(
        src + ((size_t)(b * 64 + ch) << 14) + q * 4096);
    float s = 0.f, sq = 0.f;
    for (int i = threadIdx.x; i < 1024; i += 256) {
        float4 v = p[i];
        s += v.x + v.y + v.z + v.w;
        sq = fmaf(v.x, v.x, fmaf(v.y, v.y, fmaf(v.z, v.z, fmaf(v.w, v.w, sq))));
    }
    __shared__ float sh[512];
    sh[threadIdx.x] = s;
    sh[256 + threadIdx.x] = sq;
    __syncthreads();
    for (int off = 128; off > 0; off >>= 1) {
        if ((int)threadIdx.x < off) {
            sh[threadIdx.x] += sh[threadIdx.x + off];
            sh[256 + threadIdx.x] += sh[256 + threadIdx.x + off];
        }
        __syncthreads();
    }
    if (threadIdx.x == 0) {
        atomicAdd(&statsAcc[ch * 2],     sh[0]);
        atomicAdd(&statsAcc[ch * 2 + 1], sh[256]);
    }
}

// ===== NCHW fp32 -> padded NHWC bf16 with inline-finalized BN + relu =========
__global__ __launch_bounds__(256) void packN_kernel(
    const float* __restrict__ src, const float* __restrict__ statsAcc,
    const float* __restrict__ g, const float* __restrict__ beta,
    short* __restrict__ h1N)
{
    __shared__ int lds[32 * 65];
    int bid = blockIdx.x;
    const int pxt = bid & 255;
    const int b = bid >> 8;
    const int t = threadIdx.x;
    {
        const int cw = t >> 3, pg = t & 7;
        #pragma unroll
        for (int h = 0; h < 2; h++) {
            int c = cw * 2 + h;
            float mean = statsAcc[c * 2] * (1.f / 32768.f);
            float var  = statsAcc[c * 2 + 1] * (1.f / 32768.f) - mean * mean;
            float sc = g[c] * rsqrtf(var + 1e-5f);
            float sh = beta[c] - mean * sc;
            const float* sp = src + ((size_t)(b * 64 + c) << 14) + pxt * 64 + pg * 8;
            float4 v0 = *(const float4*)sp;
            float4 v1 = *(const float4*)(sp + 4);
            float vals[8] = {v0.x, v0.y, v0.z, v0.w, v1.x, v1.y, v1.z, v1.w};
            #pragma unroll
            for (int i = 0; i < 8; i++) {
                float v = fmaxf(fmaf(vals[i], sc, sh), 0.f);
                unsigned wv = (unsigned)(unsigned short)bf16rne(v);
                if (h == 0) lds[cw * 65 + pg * 8 + i] = (int)wv;
                else        lds[cw * 65 + pg * 8 + i] |= (int)(wv << 16);
            }
        }
    }
    __syncthreads();
    {
        const int px = t >> 2, cq = t & 3;
        int wd[8];
        #pragma unroll
        for (int i = 0; i < 8; i++) wd[i] = lds[(cq * 8 + i) * 65 + px];
        int pixel = pxt * 64 + px;
        int yy = pixel >> 7, xx = pixel & 127;
        int pp = (yy + 1) * 130 + xx + 1;
        int* dp = (int*)h1N + ((size_t)b * PADPIX + pp) * 32 + cq * 8;
        *(int4*)dp = make_int4(wd[0], wd[1], wd[2], wd[3]);
        *(int4*)(dp + 4) = make_int4(wd[4], wd[5], wd[6], wd[7]);
    }
}

// ===== inline-finalized BN + relu + split o1/o2 -> d_out =====================
__global__ void norm2_kernel(const float4* __restrict__ src,
                             const float* __restrict__ statsAcc,
                             const float* __restrict__ g, const float* __restrict__ beta,
                             float4* __restrict__ out) {
    int idx4 = blockIdx.x * 256 + threadIdx.x;           // over 2*64*4096
    int q = idx4 & 4095;
    int c = (idx4 >> 12) & 63;
    int b = idx4 >> 18;
    float mean = statsAcc[c * 2] * (1.f / 32768.f);
    float var  = statsAcc[c * 2 + 1] * (1.f / 32768.f) - mean * mean;
    float sc = g[c] * rsqrtf(var + 1e-5f);
    float sh = beta[c] - mean * sc;
    float4 v = src[idx4];
    v.x = fmaxf(fmaf(v.x, sc, sh), 0.f);
    v.y = fmaxf(fmaf(v.y, sc, sh), 0.f);
    v.z = fmaxf(fmaf(v.z, sc, sh), 0.f);
    v.w = fmaxf(fmaf(v.w, sc, sh), 0.f);
    int half = c >> 5, cc = c & 31;
    out[(size_t)half * 262144 + (((size_t)(b * 32 + cc)) << 12) + q] = v;
}

extern "C" void kernel_launch(void* const* d_in, const int* in_sizes, int n_in,
                              void* d_out, int out_size, void* d_ws, size_t ws_size,
                              hipStream_t stream) {
    const float* x1 = (const float*)d_in[0];
    // d_in[1] (x1_) is unused by the reference
    const float* x2 = (const float*)d_in[2];
    const float* Wq = (const float*)d_in[3];
    const float* bq = (const float*)d_in[4];
    const float* Wk = (const float*)d_in[5];
    const float* bk = (const float*)d_in[6];
    const float* Wv = (const float*)d_in[7];
    const float* bv = (const float*)d_in[8];
    const float* W1 = (const float*)d_in[9];
    const float* g1 = (const float*)d_in[10];
    const float* b1 = (const float*)d_in[11];
    const float* W2 = (const float*)d_in[12];
    const float* g2 = (const float*)d_in[13];
    const float* b2 = (const float*)d_in[14];
    float* out = (float*)d_out;
    float* ws = (float*)d_ws;

    // workspace layout (float offsets)
    float* c1out  = ws;                        // [2][64][HW] fp32      (2,097,152)
    float* stacc  = ws + 2097152;              // 256 raw sums
    short* hcatN  = (short*)(ws + 2097408);    // [2][PADPIX][128] bf16 (2,163,200 f)
    short* h1N    = (short*)(ws + 4260608);    // [2][PADPIX][64]  bf16 (1,081,600 f)
    short* Wb1    = (short*)(ws + 5342208);    // 73728 shorts = 36864 f
    short* Wb2    = (short*)(ws + 5379072);    // 36864 shorts = 18432 f
    short* Wbk    = (short*)(ws + 5397504);    // 9216 shorts  =  4608 f

    // K1: weight prep + border zeroing + stats-acc zero
    k1_kernel<<<566, 256, 0, stream>>>(W1, W2, Wk, Wb1, Wb2, Wbk, hcatN, h1N, stacc);

    // front: upsample + Kf conv + qconv + gate, fused -> hcatN (both halves)
    front_kernel<<<1024, 256, 0, stream>>>(x1, Wbk, bk, Wq, bq, x2, Wv, bv, hcatN);

    // conv1 128->64 (branchless, MB=1 -> grid 1024)
    convmfma_kernel<128, 128, 64, 2, 2, 1><<<1024, 256, 0, stream>>>(hcatN, Wb1, c1out);
    bnstats_kernel<<<512, 256, 0, stream>>>(c1out, stacc);
    packN_kernel<<<512, 256, 0, stream>>>(c1out, stacc, g1, b1, h1N);

    // conv2 64->64 (branchless, MB=1 -> grid 1024)
    convmfma_kernel<64, 64, 64, 2, 2, 1><<<1024, 256, 0, stream>>>(h1N, Wb2, c1out);
    bnstats_kernel<<<512, 256, 0, stream>>>(c1out, stacc + 128);
    norm2_kernel<<<2048, 256, 0, stream>>>((const float4*)c1out, stacc + 128, g2, b2,
                                           (float4*)out);
}